// Round 1
// baseline (481.384 us; speedup 1.0000x reference)
//
#include <hip/hip_runtime.h>
#include <math.h>

// Model dims
#define BB 8
#define TT 150
#define DD 30
#define HH 5
#define HD 6
#define LL 3
#define NI 40          // B*H heads per stream
#define ROWF (TT*BB*DD)  // 36000 floats per [T,B,D] buffer

__device__ __forceinline__ float wsum(float v) {
    #pragma unroll
    for (int m = 32; m > 0; m >>= 1) v += __shfl_xor(v, m, 64);
    return v;
}
__device__ __forceinline__ float wmax(float v) {
    #pragma unroll
    for (int m = 32; m > 0; m >>= 1) v = fmaxf(v, __shfl_xor(v, m, 64));
    return v;
}

// out[t*240 + b*30 + d] = sum_j x[b*T*Cin + t*Cin + j] * W[d*Cin + j]
__global__ __launch_bounds__(256) void proj_kernel(const float* __restrict__ x,
                                                   const float* __restrict__ W,
                                                   float* __restrict__ out, int Cin) {
    int idx = blockIdx.x * 256 + threadIdx.x;
    if (idx >= ROWF) return;
    int t = idx / (BB * DD);
    int r = idx % (BB * DD);
    int b = r / DD, d = r % DD;
    const float* xr = x + ((size_t)b * TT + t) * Cin;
    const float* wr = W + (size_t)d * Cin;
    float acc = 0.f;
    for (int j = 0; j < Cin; j++) acc += xr[j] * wr[j];
    out[idx] = acc;
}

// h[s][...] = pl[...] for s=0,1
__global__ __launch_bounds__(256) void bcast_kernel(const float* __restrict__ pl,
                                                    float* __restrict__ h) {
    int idx = blockIdx.x * 256 + threadIdx.x;
    if (idx < 2 * ROWF) h[idx] = pl[idx % ROWF];
}

// Per (s, t, b): LN the x/xk/xv rows, project to q/k/v, store in head layout
// q/k/v: [2][40][150][6]
__global__ __launch_bounds__(64) void lnqkv_kernel(
    const float* __restrict__ h, const float* __restrict__ pa, const float* __restrict__ pv,
    const float* __restrict__ in_w, const float* __restrict__ in_b,
    const float* __restrict__ n1g, const float* __restrict__ n1b, int l,
    float* __restrict__ q, float* __restrict__ k, float* __restrict__ v) {
    int blk = blockIdx.x;            // [0, 2400)
    int s = blk / 1200;
    int tb = blk % 1200;
    int t = tb / BB, b = tb % BB;
    int lane = threadIdx.x;
    const float* xk = (s == 0) ? pa : pv;
    const float* xv = (s == 0) ? pv : pa;
    int po = s * LL + l;
    const float* iw = in_w + (size_t)po * 90 * 30;
    const float* ib = in_b + (size_t)po * 90;
    const float* g  = n1g + (size_t)po * 30;
    const float* bbv = n1b + (size_t)po * 30;
    __shared__ float xn[3][30];
    const float* rows[3];
    rows[0] = h + (size_t)s * ROWF + (size_t)tb * 30;
    rows[1] = xk + (size_t)tb * 30;
    rows[2] = xv + (size_t)tb * 30;
    for (int r = 0; r < 3; r++) {
        float xval = (lane < 30) ? rows[r][lane] : 0.f;
        float mean = wsum(xval) * (1.f / 30.f);
        float dv = (lane < 30) ? (xval - mean) : 0.f;
        float var = wsum(dv * dv) * (1.f / 30.f);
        float inv = rsqrtf(var + 1e-5f);
        if (lane < 30) xn[r][lane] = dv * inv * g[lane] + bbv[lane];
    }
    __syncthreads();
    for (int o = lane; o < 90; o += 64) {
        int which = o / 30, dd = o % 30;
        const float* wr = iw + o * 30;
        const float* xr = xn[which];
        float acc = 0.f;
        #pragma unroll 6
        for (int j = 0; j < 30; j++) acc += wr[j] * xr[j];
        acc += ib[o];
        if (which == 0) acc *= 0.40824829046386307f;  // HD^-0.5
        int i = b * HH + dd / HD, hd = dd % HD;
        float* dst = (which == 0) ? q : ((which == 1) ? k : v);
        dst[((size_t)s * NI + i) * (TT * HD) + t * HD + hd] = acc;
    }
}

// One wave per (s, i, a): scores over b (mean+max over c fused in one c-pass),
// softmax over b, attn[i,a,:] = sum_b p_b * q[i,b,:]; write to [t][b][d] layout.
__global__ __launch_bounds__(64) void score_kernel(
    const float* __restrict__ q, const float* __restrict__ k, const float* __restrict__ v,
    float* __restrict__ attn) {
    int blk = blockIdx.x;            // [0, 12000)
    int s = blk / (NI * TT);
    int r = blk % (NI * TT);
    int i = r / TT, a = r % TT;
    int lane = threadIdx.x;
    __shared__ __align__(16) float vs[TT * 8];
    __shared__ float ks[TT * HD];
    __shared__ float qs[TT * HD];
    const float* qb = q + ((size_t)s * NI + i) * (TT * HD);
    const float* kb = k + ((size_t)s * NI + i) * (TT * HD);
    const float* vb = v + ((size_t)s * NI + i) * (TT * HD);
    for (int idx = lane; idx < TT * HD; idx += 64) {
        qs[idx] = qb[idx];
        ks[idx] = kb[idx];
        vs[(idx / HD) * 8 + (idx % HD)] = vb[idx];
    }
    __syncthreads();
    float qa[HD];
    #pragma unroll
    for (int t2 = 0; t2 < HD; t2++) qa[t2] = qs[a * HD + t2];
    float w[3][HD], mx[3], sm[3];
    int bidx[3];
    #pragma unroll
    for (int rr = 0; rr < 3; rr++) {
        int b = lane + rr * 64;
        bidx[rr] = b;
        #pragma unroll
        for (int t2 = 0; t2 < HD; t2++)
            w[rr][t2] = (b < TT) ? qa[t2] * ks[b * HD + t2] : 0.f;
        mx[rr] = -INFINITY;
        sm[rr] = 0.f;
    }
    for (int c = 0; c < TT; c++) {
        float4 v0 = *reinterpret_cast<const float4*>(&vs[c * 8]);
        float2 v1 = *reinterpret_cast<const float2*>(&vs[c * 8 + 4]);
        #pragma unroll
        for (int rr = 0; rr < 3; rr++) {
            float d = w[rr][0] * v0.x + w[rr][1] * v0.y + w[rr][2] * v0.z +
                      w[rr][3] * v0.w + w[rr][4] * v1.x + w[rr][5] * v1.y;
            sm[rr] += d;
            mx[rr] = fmaxf(mx[rr], d);
        }
    }
    float sc[3];
    float lmax = -INFINITY;
    #pragma unroll
    for (int rr = 0; rr < 3; rr++) {
        if (bidx[rr] < TT) {
            sc[rr] = sm[rr] * (1.f / 150.f) + mx[rr];
            lmax = fmaxf(lmax, sc[rr]);
        } else {
            sc[rr] = -INFINITY;
        }
    }
    float gmax = wmax(lmax);
    float esum = 0.f;
    float acc[HD] = {0.f, 0.f, 0.f, 0.f, 0.f, 0.f};
    #pragma unroll
    for (int rr = 0; rr < 3; rr++) {
        if (bidx[rr] < TT) {
            float e = expf(sc[rr] - gmax);
            esum += e;
            #pragma unroll
            for (int t2 = 0; t2 < HD; t2++) acc[t2] += e * qs[bidx[rr] * HD + t2];
        }
    }
    esum = wsum(esum);
    #pragma unroll
    for (int t2 = 0; t2 < HD; t2++) acc[t2] = wsum(acc[t2]);
    if (lane == 0) {
        float inv = 1.f / esum;
        int bo = i / HH, ho = i % HH;
        float* dst = attn + (size_t)s * ROWF + a * (BB * DD) + bo * DD + ho * HD;
        #pragma unroll
        for (int t2 = 0; t2 < HD; t2++) dst[t2] = acc[t2] * inv;
    }
}

// Per (s, t, b): x1 = h + attn@ow.T + ob; h = x1 + lin2(relu(lin1(LN(x1))))
__global__ __launch_bounds__(64) void outffn_kernel(
    const float* __restrict__ attn,
    const float* __restrict__ out_w, const float* __restrict__ out_b,
    const float* __restrict__ l1w, const float* __restrict__ l1b,
    const float* __restrict__ l2w, const float* __restrict__ l2b,
    const float* __restrict__ n2g, const float* __restrict__ n2b, int l,
    float* __restrict__ h) {
    int blk = blockIdx.x;            // [0, 2400)
    int s = blk / 1200;
    int tb = blk % 1200;
    int lane = threadIdx.x;
    int po = s * LL + l;
    const float* ow = out_w + (size_t)po * 900;
    const float* ob = out_b + (size_t)po * 30;
    const float* w1 = l1w + (size_t)po * 120 * 30;
    const float* b1 = l1b + (size_t)po * 120;
    const float* w2 = l2w + (size_t)po * 30 * 120;
    const float* b2 = l2b + (size_t)po * 30;
    const float* g  = n2g + (size_t)po * 30;
    const float* bbv = n2b + (size_t)po * 30;
    float* hrow = h + (size_t)s * ROWF + (size_t)tb * 30;
    const float* arow = attn + (size_t)s * ROWF + (size_t)tb * 30;
    __shared__ float ar[30], x1[30], xn[30], hid[120];
    if (lane < 30) ar[lane] = arow[lane];
    __syncthreads();
    float x1v = 0.f;
    if (lane < 30) {
        const float* wr = ow + lane * 30;
        float acc = 0.f;
        #pragma unroll 6
        for (int j = 0; j < 30; j++) acc += wr[j] * ar[j];
        x1v = hrow[lane] + acc + ob[lane];
        x1[lane] = x1v;
    }
    float mean = wsum(x1v) * (1.f / 30.f);
    float dv = (lane < 30) ? (x1v - mean) : 0.f;
    float var = wsum(dv * dv) * (1.f / 30.f);
    float inv = rsqrtf(var + 1e-5f);
    if (lane < 30) xn[lane] = dv * inv * g[lane] + bbv[lane];
    __syncthreads();
    for (int o = lane; o < 120; o += 64) {
        const float* wr = w1 + o * 30;
        float acc = 0.f;
        #pragma unroll 6
        for (int j = 0; j < 30; j++) acc += wr[j] * xn[j];
        hid[o] = fmaxf(acc + b1[o], 0.f);
    }
    __syncthreads();
    if (lane < 30) {
        const float* wr = w2 + lane * 120;
        float acc = 0.f;
        #pragma unroll 8
        for (int j = 0; j < 120; j++) acc += wr[j] * hid[j];
        hrow[lane] = x1[lane] + acc + b2[lane];
    }
}

// Final head: last_hs, proj MLP + residual, scalar out. Writes all 488 outputs.
__global__ __launch_bounds__(64) void head_kernel(
    const float* __restrict__ h,
    const float* __restrict__ p1w, const float* __restrict__ p1b,
    const float* __restrict__ p2w, const float* __restrict__ p2b,
    const float* __restrict__ ow, const float* __restrict__ ob,
    float* __restrict__ out) {
    int lane = threadIdx.x;
    __shared__ float lh[480], hid[480], pr[480];
    for (int idx = lane; idx < 480; idx += 64) {
        int b = idx / 60, j = idx % 60;
        int s = j / 30, d = j % 30;
        float vv = h[(size_t)s * ROWF + 149 * (BB * DD) + b * DD + d];
        lh[idx] = vv;
        out[8 + idx] = vv;   // last_hs output
    }
    __syncthreads();
    for (int idx = lane; idx < 480; idx += 64) {
        int b = idx / 60, o = idx % 60;
        const float* wr = p1w + o * 60;
        float acc = p1b[o];
        for (int j = 0; j < 60; j++) acc += wr[j] * lh[b * 60 + j];
        hid[idx] = fmaxf(acc, 0.f);
    }
    __syncthreads();
    for (int idx = lane; idx < 480; idx += 64) {
        int b = idx / 60, d = idx % 60;
        const float* wr = p2w + d * 60;
        float acc = p2b[d];
        for (int j = 0; j < 60; j++) acc += wr[j] * hid[b * 60 + j];
        pr[idx] = acc + lh[idx];
    }
    __syncthreads();
    if (lane < 8) {
        float acc = ob[0];
        for (int j = 0; j < 60; j++) acc += pr[lane * 60 + j] * ow[j];
        out[lane] = acc;     // out output
    }
}

extern "C" void kernel_launch(void* const* d_in, const int* in_sizes, int n_in,
                              void* d_out, int out_size, void* d_ws, size_t ws_size,
                              hipStream_t stream) {
    const float* x_l   = (const float*)d_in[0];
    const float* x_a   = (const float*)d_in[1];
    const float* x_v   = (const float*)d_in[2];
    const float* Wl    = (const float*)d_in[3];
    const float* Wa    = (const float*)d_in[4];
    const float* Wv    = (const float*)d_in[5];
    const float* in_w  = (const float*)d_in[6];
    const float* in_b  = (const float*)d_in[7];
    const float* out_w = (const float*)d_in[8];
    const float* out_b = (const float*)d_in[9];
    const float* l1w   = (const float*)d_in[10];
    const float* l1b   = (const float*)d_in[11];
    const float* l2w   = (const float*)d_in[12];
    const float* l2b   = (const float*)d_in[13];
    const float* n1g   = (const float*)d_in[14];
    const float* n1b   = (const float*)d_in[15];
    const float* n2g   = (const float*)d_in[16];
    const float* n2b   = (const float*)d_in[17];
    const float* p1w   = (const float*)d_in[18];
    const float* p1b   = (const float*)d_in[19];
    const float* p2w   = (const float*)d_in[20];
    const float* p2b   = (const float*)d_in[21];
    const float* oww   = (const float*)d_in[22];
    const float* obb   = (const float*)d_in[23];

    float* ws = (float*)d_ws;
    float* pl = ws;                   // 36000
    float* pa = ws + 36000;           // 36000
    float* pv = ws + 72000;           // 36000
    float* h  = ws + 108000;          // 72000 ([2][T][B][D])
    float* q  = ws + 180000;          // 72000 ([2][40][150][6])
    float* kk = ws + 252000;          // 72000
    float* vv = ws + 324000;          // 72000
    float* at = ws + 396000;          // 72000

    proj_kernel<<<(ROWF + 255) / 256, 256, 0, stream>>>(x_l, Wl, pl, 300);
    proj_kernel<<<(ROWF + 255) / 256, 256, 0, stream>>>(x_a, Wa, pa, 74);
    proj_kernel<<<(ROWF + 255) / 256, 256, 0, stream>>>(x_v, Wv, pv, 35);
    bcast_kernel<<<(2 * ROWF + 255) / 256, 256, 0, stream>>>(pl, h);

    for (int l = 0; l < LL; l++) {
        lnqkv_kernel<<<2400, 64, 0, stream>>>(h, pa, pv, in_w, in_b, n1g, n1b, l, q, kk, vv);
        score_kernel<<<12000, 64, 0, stream>>>(q, kk, vv, at);
        outffn_kernel<<<2400, 64, 0, stream>>>(at, out_w, out_b, l1w, l1b, l2w, l2b,
                                               n2g, n2b, l, h);
    }
    head_kernel<<<1, 64, 0, stream>>>(h, p1w, p1b, p2w, p2b, oww, obb, (float*)d_out);
}

// Round 2
// 398.742 us; speedup vs baseline: 1.2073x; 1.2073x over previous
//
#include <hip/hip_runtime.h>
#include <math.h>

// Model dims
#define BB 8
#define TT 150
#define DD 30
#define HH 5
#define HD 6
#define LL 3
#define NI 40          // B*H heads per stream
#define ROWF (TT*BB*DD)  // 36000 floats per [T,B,D] buffer

typedef _Float16 half8 __attribute__((ext_vector_type(8)));
typedef float f32x16 __attribute__((ext_vector_type(16)));

__device__ __forceinline__ float wsum(float v) {
    #pragma unroll
    for (int m = 32; m > 0; m >>= 1) v += __shfl_xor(v, m, 64);
    return v;
}

// out[t*240 + b*30 + d] = sum_j x[b*T*Cin + t*Cin + j] * W[d*Cin + j]
__global__ __launch_bounds__(256) void proj_kernel(const float* __restrict__ x,
                                                   const float* __restrict__ W,
                                                   float* __restrict__ out, int Cin) {
    int idx = blockIdx.x * 256 + threadIdx.x;
    if (idx >= ROWF) return;
    int t = idx / (BB * DD);
    int r = idx % (BB * DD);
    int b = r / DD, d = r % DD;
    const float* xr = x + ((size_t)b * TT + t) * Cin;
    const float* wr = W + (size_t)d * Cin;
    float acc = 0.f;
    for (int j = 0; j < Cin; j++) acc += xr[j] * wr[j];
    out[idx] = acc;
}

// h[s][...] = pl[...] for s=0,1
__global__ __launch_bounds__(256) void bcast_kernel(const float* __restrict__ pl,
                                                    float* __restrict__ h) {
    int idx = blockIdx.x * 256 + threadIdx.x;
    if (idx < 2 * ROWF) h[idx] = pl[idx % ROWF];
}

// Per (s, t, b): LN the x/xk/xv rows, project to q/k/v, store in head layout
// q/k/v: [2][40][150][6]
__global__ __launch_bounds__(64) void lnqkv_kernel(
    const float* __restrict__ h, const float* __restrict__ pa, const float* __restrict__ pv,
    const float* __restrict__ in_w, const float* __restrict__ in_b,
    const float* __restrict__ n1g, const float* __restrict__ n1b, int l,
    float* __restrict__ q, float* __restrict__ k, float* __restrict__ v) {
    int blk = blockIdx.x;            // [0, 2400)
    int s = blk / 1200;
    int tb = blk % 1200;
    int t = tb / BB, b = tb % BB;
    int lane = threadIdx.x;
    const float* xk = (s == 0) ? pa : pv;
    const float* xv = (s == 0) ? pv : pa;
    int po = s * LL + l;
    const float* iw = in_w + (size_t)po * 90 * 30;
    const float* ib = in_b + (size_t)po * 90;
    const float* g  = n1g + (size_t)po * 30;
    const float* bbv = n1b + (size_t)po * 30;
    __shared__ float xn[3][30];
    const float* rows[3];
    rows[0] = h + (size_t)s * ROWF + (size_t)tb * 30;
    rows[1] = xk + (size_t)tb * 30;
    rows[2] = xv + (size_t)tb * 30;
    for (int r = 0; r < 3; r++) {
        float xval = (lane < 30) ? rows[r][lane] : 0.f;
        float mean = wsum(xval) * (1.f / 30.f);
        float dv = (lane < 30) ? (xval - mean) : 0.f;
        float var = wsum(dv * dv) * (1.f / 30.f);
        float inv = rsqrtf(var + 1e-5f);
        if (lane < 30) xn[r][lane] = dv * inv * g[lane] + bbv[lane];
    }
    __syncthreads();
    for (int o = lane; o < 90; o += 64) {
        int which = o / 30, dd = o % 30;
        const float* wr = iw + o * 30;
        const float* xr = xn[which];
        float acc = 0.f;
        #pragma unroll 6
        for (int j = 0; j < 30; j++) acc += wr[j] * xr[j];
        acc += ib[o];
        if (which == 0) acc *= 0.40824829046386307f;  // HD^-0.5
        int i = b * HH + dd / HD, hd = dd % HD;
        float* dst = (which == 0) ? q : ((which == 1) ? k : v);
        dst[((size_t)s * NI + i) * (TT * HD) + t * HD + hd] = acc;
    }
}

// MFMA score kernel. One wave per (s, i, a-pair). Per a:
//   D[c,b] = sum_t (qa[t]*v[c,t]) * k[b,t]  via mfma_f32_32x32x16_f16,
//   M = c (rows, reduced by mean+max), N = b (cols, softmax), K = 6 (padded to 16).
// C/D layout: col = lane&31, row = (reg&3) + 8*(reg>>2) + 4*(lane>>5).
// A layout:  A[m = lane&31][k = (lane>>5)*8 + j]  (j = 0..7)
// B layout:  B[k = (lane>>5)*8 + j][n = lane&31]
// -> lanes with lane>=32 carry k=8..15 which is all zero padding.
__global__ __launch_bounds__(64) void score_mfma_kernel(
    const float* __restrict__ q, const float* __restrict__ k, const float* __restrict__ v,
    float* __restrict__ attn) {
    int blk = blockIdx.x;            // [0, 6000)
    int s = blk / 3000;
    int r = blk % 3000;
    int i = r / 75;
    int g = r % 75;
    int lane = threadIdx.x;
    int lo = lane & 31, h = lane >> 5;

    const float* qb = q + ((size_t)s * NI + i) * (TT * HD);
    const float* kb = k + ((size_t)s * NI + i) * (TT * HD);
    const float* vb = v + ((size_t)s * NI + i) * (TT * HD);

    __shared__ float qs[TT * HD];
    for (int idx = lane; idx < TT * HD; idx += 64) qs[idx] = qb[idx];

    // Stage K fragments (B-operand) and V rows (fp32, scaled per-a later).
    float vrow[5][6];
    half8 bfrag[5];
    #pragma unroll
    for (int nt = 0; nt < 5; nt++) {
        int rr = nt * 32 + lo;
        bool live = (h == 0) && (rr < TT);
        #pragma unroll
        for (int t = 0; t < 6; t++) {
            float kv = live ? kb[rr * 6 + t] : 0.f;
            bfrag[nt][t] = (_Float16)kv;
            vrow[nt][t] = live ? vb[rr * 6 + t] : 0.f;
        }
        bfrag[nt][6] = (_Float16)0.f;
        bfrag[nt][7] = (_Float16)0.f;
    }
    __syncthreads();

    for (int ap = 0; ap < 2; ap++) {
        int a = g * 2 + ap;
        float qa[6];
        #pragma unroll
        for (int t = 0; t < 6; t++) qa[t] = qs[a * 6 + t];
        half8 afrag[5];
        #pragma unroll
        for (int nt = 0; nt < 5; nt++) {
            #pragma unroll
            for (int t = 0; t < 6; t++)
                afrag[nt][t] = (_Float16)(qa[t] * vrow[nt][t]);
            afrag[nt][6] = (_Float16)0.f;
            afrag[nt][7] = (_Float16)0.f;
        }
        float fsc[5];
        #pragma unroll
        for (int nb = 0; nb < 5; nb++) {
            float runmax = -INFINITY, runsum = 0.f;
            #pragma unroll
            for (int ma = 0; ma < 5; ma++) {
                f32x16 acc;
                #pragma unroll
                for (int rr2 = 0; rr2 < 16; rr2++) acc[rr2] = 0.f;
                acc = __builtin_amdgcn_mfma_f32_32x32x16_f16(afrag[ma], bfrag[nb], acc, 0, 0, 0);
                #pragma unroll
                for (int rr2 = 0; rr2 < 16; rr2++) {
                    float val = acc[rr2];
                    runsum += val;
                    // pad rows: c = 128 + (reg&3)+8*(reg>>2)+4*h >= 150 only for ma==4
                    bool dead = (ma == 4) && (rr2 >= 12 || (rr2 >= 10 && h == 1));
                    runmax = fmaxf(runmax, dead ? -INFINITY : val);
                }
            }
            runsum += __shfl_xor(runsum, 32, 64);
            runmax = fmaxf(runmax, __shfl_xor(runmax, 32, 64));
            int b = nb * 32 + lo;
            fsc[nb] = (b < TT) ? (runsum * (1.f / 150.f) + runmax) : -INFINITY;
        }
        // softmax over b (each 32-lane group holds the full b-range, halves duplicate)
        float m = fsc[0];
        #pragma unroll
        for (int nb = 1; nb < 5; nb++) m = fmaxf(m, fsc[nb]);
        #pragma unroll
        for (int msk = 16; msk > 0; msk >>= 1) m = fmaxf(m, __shfl_xor(m, msk, 64));
        float e[5], es = 0.f;
        #pragma unroll
        for (int nb = 0; nb < 5; nb++) { e[nb] = __expf(fsc[nb] - m); es += e[nb]; }
        #pragma unroll
        for (int msk = 16; msk > 0; msk >>= 1) es += __shfl_xor(es, msk, 64);
        // attn[a,:] = sum_b p_b * q[b,:]
        float acc6[6] = {0.f, 0.f, 0.f, 0.f, 0.f, 0.f};
        #pragma unroll
        for (int nb = 0; nb < 5; nb++) {
            int b = nb * 32 + lo;
            int bi = (b < TT) ? b : 0;
            float w = e[nb];
            #pragma unroll
            for (int t = 0; t < 6; t++) acc6[t] += w * qs[bi * 6 + t];
        }
        #pragma unroll
        for (int msk = 16; msk > 0; msk >>= 1) {
            #pragma unroll
            for (int t = 0; t < 6; t++) acc6[t] += __shfl_xor(acc6[t], msk, 64);
        }
        if (lane == 0) {
            float inv = 1.f / es;
            int bo = i / HH, ho = i % HH;
            float* dst = attn + (size_t)s * ROWF + a * (BB * DD) + bo * DD + ho * HD;
            #pragma unroll
            for (int t = 0; t < 6; t++) dst[t] = acc6[t] * inv;
        }
    }
}

// Per (s, t, b): x1 = h + attn@ow.T + ob; h = x1 + lin2(relu(lin1(LN(x1))))
__global__ __launch_bounds__(64) void outffn_kernel(
    const float* __restrict__ attn,
    const float* __restrict__ out_w, const float* __restrict__ out_b,
    const float* __restrict__ l1w, const float* __restrict__ l1b,
    const float* __restrict__ l2w, const float* __restrict__ l2b,
    const float* __restrict__ n2g, const float* __restrict__ n2b, int l,
    float* __restrict__ h) {
    int blk = blockIdx.x;            // [0, 2400)
    int s = blk / 1200;
    int tb = blk % 1200;
    int lane = threadIdx.x;
    int po = s * LL + l;
    const float* ow = out_w + (size_t)po * 900;
    const float* ob = out_b + (size_t)po * 30;
    const float* w1 = l1w + (size_t)po * 120 * 30;
    const float* b1 = l1b + (size_t)po * 120;
    const float* w2 = l2w + (size_t)po * 30 * 120;
    const float* b2 = l2b + (size_t)po * 30;
    const float* g  = n2g + (size_t)po * 30;
    const float* bbv = n2b + (size_t)po * 30;
    float* hrow = h + (size_t)s * ROWF + (size_t)tb * 30;
    const float* arow = attn + (size_t)s * ROWF + (size_t)tb * 30;
    __shared__ float ar[30], x1[30], xn[30], hid[120];
    if (lane < 30) ar[lane] = arow[lane];
    __syncthreads();
    float x1v = 0.f;
    if (lane < 30) {
        const float* wr = ow + lane * 30;
        float acc = 0.f;
        #pragma unroll 6
        for (int j = 0; j < 30; j++) acc += wr[j] * ar[j];
        x1v = hrow[lane] + acc + ob[lane];
        x1[lane] = x1v;
    }
    float mean = wsum(x1v) * (1.f / 30.f);
    float dv = (lane < 30) ? (x1v - mean) : 0.f;
    float var = wsum(dv * dv) * (1.f / 30.f);
    float inv = rsqrtf(var + 1e-5f);
    if (lane < 30) xn[lane] = dv * inv * g[lane] + bbv[lane];
    __syncthreads();
    for (int o = lane; o < 120; o += 64) {
        const float* wr = w1 + o * 30;
        float acc = 0.f;
        #pragma unroll 6
        for (int j = 0; j < 30; j++) acc += wr[j] * xn[j];
        hid[o] = fmaxf(acc + b1[o], 0.f);
    }
    __syncthreads();
    if (lane < 30) {
        const float* wr = w2 + lane * 120;
        float acc = 0.f;
        #pragma unroll 8
        for (int j = 0; j < 120; j++) acc += wr[j] * hid[j];
        hrow[lane] = x1[lane] + acc + b2[lane];
    }
}

// Final head: last_hs, proj MLP + residual, scalar out. Writes all 488 outputs.
__global__ __launch_bounds__(64) void head_kernel(
    const float* __restrict__ h,
    const float* __restrict__ p1w, const float* __restrict__ p1b,
    const float* __restrict__ p2w, const float* __restrict__ p2b,
    const float* __restrict__ ow, const float* __restrict__ ob,
    float* __restrict__ out) {
    int lane = threadIdx.x;
    __shared__ float lh[480], hid[480], pr[480];
    for (int idx = lane; idx < 480; idx += 64) {
        int b = idx / 60, j = idx % 60;
        int s = j / 30, d = j % 30;
        float vv = h[(size_t)s * ROWF + 149 * (BB * DD) + b * DD + d];
        lh[idx] = vv;
        out[8 + idx] = vv;   // last_hs output
    }
    __syncthreads();
    for (int idx = lane; idx < 480; idx += 64) {
        int b = idx / 60, o = idx % 60;
        const float* wr = p1w + o * 60;
        float acc = p1b[o];
        for (int j = 0; j < 60; j++) acc += wr[j] * lh[b * 60 + j];
        hid[idx] = fmaxf(acc, 0.f);
    }
    __syncthreads();
    for (int idx = lane; idx < 480; idx += 64) {
        int b = idx / 60, d = idx % 60;
        const float* wr = p2w + d * 60;
        float acc = p2b[d];
        for (int j = 0; j < 60; j++) acc += wr[j] * hid[b * 60 + j];
        pr[idx] = acc + lh[idx];
    }
    __syncthreads();
    if (lane < 8) {
        float acc = ob[0];
        for (int j = 0; j < 60; j++) acc += pr[lane * 60 + j] * ow[j];
        out[lane] = acc;     // out output
    }
}

extern "C" void kernel_launch(void* const* d_in, const int* in_sizes, int n_in,
                              void* d_out, int out_size, void* d_ws, size_t ws_size,
                              hipStream_t stream) {
    const float* x_l   = (const float*)d_in[0];
    const float* x_a   = (const float*)d_in[1];
    const float* x_v   = (const float*)d_in[2];
    const float* Wl    = (const float*)d_in[3];
    const float* Wa    = (const float*)d_in[4];
    const float* Wv    = (const float*)d_in[5];
    const float* in_w  = (const float*)d_in[6];
    const float* in_b  = (const float*)d_in[7];
    const float* out_w = (const float*)d_in[8];
    const float* out_b = (const float*)d_in[9];
    const float* l1w   = (const float*)d_in[10];
    const float* l1b   = (const float*)d_in[11];
    const float* l2w   = (const float*)d_in[12];
    const float* l2b   = (const float*)d_in[13];
    const float* n1g   = (const float*)d_in[14];
    const float* n1b   = (const float*)d_in[15];
    const float* n2g   = (const float*)d_in[16];
    const float* n2b   = (const float*)d_in[17];
    const float* p1w   = (const float*)d_in[18];
    const float* p1b   = (const float*)d_in[19];
    const float* p2w   = (const float*)d_in[20];
    const float* p2b   = (const float*)d_in[21];
    const float* oww   = (const float*)d_in[22];
    const float* obb   = (const float*)d_in[23];

    float* ws = (float*)d_ws;
    float* pl = ws;                   // 36000
    float* pa = ws + 36000;           // 36000
    float* pv = ws + 72000;           // 36000
    float* h  = ws + 108000;          // 72000 ([2][T][B][D])
    float* q  = ws + 180000;          // 72000 ([2][40][150][6])
    float* kk = ws + 252000;          // 72000
    float* vv = ws + 324000;          // 72000
    float* at = ws + 396000;          // 72000

    proj_kernel<<<(ROWF + 255) / 256, 256, 0, stream>>>(x_l, Wl, pl, 300);
    proj_kernel<<<(ROWF + 255) / 256, 256, 0, stream>>>(x_a, Wa, pa, 74);
    proj_kernel<<<(ROWF + 255) / 256, 256, 0, stream>>>(x_v, Wv, pv, 35);
    bcast_kernel<<<(2 * ROWF + 255) / 256, 256, 0, stream>>>(pl, h);

    for (int l = 0; l < LL; l++) {
        lnqkv_kernel<<<2400, 64, 0, stream>>>(h, pa, pv, in_w, in_b, n1g, n1b, l, q, kk, vv);
        score_mfma_kernel<<<6000, 64, 0, stream>>>(q, kk, vv, at);
        outffn_kernel<<<2400, 64, 0, stream>>>(at, out_w, out_b, l1w, l1b, l2w, l2b,
                                               n2g, n2b, l, h);
    }
    head_kernel<<<1, 64, 0, stream>>>(h, p1w, p1b, p2w, p2b, oww, obb, (float*)d_out);
}

// Round 3
// 283.215 us; speedup vs baseline: 1.6997x; 1.4079x over previous
//
#include <hip/hip_runtime.h>
#include <math.h>

// Model dims
#define BB 8
#define TT 150
#define DD 30
#define HH 5
#define HD 6
#define LL 3
#define NI 40          // B*H heads per stream
#define ROWF (TT*BB*DD)  // 36000 floats per [T,B,D] buffer

typedef _Float16 half8 __attribute__((ext_vector_type(8)));
typedef float f32x16 __attribute__((ext_vector_type(16)));

__device__ __forceinline__ float wsum(float v) {
    #pragma unroll
    for (int m = 32; m > 0; m >>= 1) v += __shfl_xor(v, m, 64);
    return v;
}

// One wave per (t,b) row; 4 waves/block. out[t*240+b*30+d] = x[b,t,:]·W[d,:]
__global__ __launch_bounds__(256) void proj_kernel(const float* __restrict__ x,
                                                   const float* __restrict__ W,
                                                   float* __restrict__ out, int Cin) {
    int w = threadIdx.x >> 6, lane = threadIdx.x & 63;
    int unit = blockIdx.x * 4 + w;          // [0,1200)
    int t = unit / BB, b = unit % BB;
    __shared__ float xr[4][304];
    const float* xp = x + ((size_t)b * TT + t) * Cin;
    for (int j = lane; j < Cin; j += 64) xr[w][j] = xp[j];
    __syncthreads();
    int d = lane >> 1, jh = lane & 1;
    int h1 = Cin >> 1;
    int j0 = jh ? h1 : 0, j1 = jh ? Cin : h1;
    const float* wr = W + (size_t)(d < DD ? d : 0) * Cin;
    float acc = 0.f;
    for (int j = j0; j < j1; j++) acc += xr[w][j] * wr[j];
    acc += __shfl_xor(acc, 1, 64);
    if (jh == 0 && d < DD) out[t * (BB * DD) + b * DD + d] = acc;
}

// One wave per (s,tb); 4 waves/block. LN rows, project to q/k/v head layout.
__global__ __launch_bounds__(256) void lnqkv_kernel(
    const float* __restrict__ h, const float* __restrict__ pl,
    const float* __restrict__ pa, const float* __restrict__ pv,
    const float* __restrict__ in_w, const float* __restrict__ in_b,
    const float* __restrict__ n1g, const float* __restrict__ n1b, int l,
    float* __restrict__ q, float* __restrict__ k, float* __restrict__ v) {
    int w = threadIdx.x >> 6, lane = threadIdx.x & 63;
    int unit = blockIdx.x * 4 + w;          // [0,2400)
    int s = unit / 1200, tb = unit % 1200;
    int t = tb / BB, b = tb % BB;
    const float* xk = (s == 0) ? pa : pv;
    const float* xv = (s == 0) ? pv : pa;
    int po = s * LL + l;
    const float* iw = in_w + (size_t)po * 90 * 30;
    const float* ib = in_b + (size_t)po * 90;
    const float* g  = n1g + (size_t)po * 30;
    const float* bbv = n1b + (size_t)po * 30;
    __shared__ float xn[4][3][30];
    const float* rows[3];
    rows[0] = (l == 0) ? (pl + (size_t)tb * 30) : (h + (size_t)s * ROWF + (size_t)tb * 30);
    rows[1] = xk + (size_t)tb * 30;
    rows[2] = xv + (size_t)tb * 30;
    for (int r = 0; r < 3; r++) {
        float xval = (lane < 30) ? rows[r][lane] : 0.f;
        float mean = wsum(xval) * (1.f / 30.f);
        float dv = (lane < 30) ? (xval - mean) : 0.f;
        float var = wsum(dv * dv) * (1.f / 30.f);
        float inv = rsqrtf(var + 1e-5f);
        if (lane < 30) xn[w][r][lane] = dv * inv * g[lane] + bbv[lane];
    }
    __syncthreads();
    for (int o = lane; o < 90; o += 64) {
        int which = o / 30, dd = o % 30;
        const float* wr = iw + o * 30;
        const float* xr = xn[w][which];
        float acc = 0.f;
        #pragma unroll 6
        for (int j = 0; j < 30; j++) acc += wr[j] * xr[j];
        acc += ib[o];
        if (which == 0) acc *= 0.40824829046386307f;  // HD^-0.5
        int i = b * HH + dd / HD, hd = dd % HD;
        float* dst = (which == 0) ? q : ((which == 1) ? k : v);
        dst[((size_t)s * NI + i) * (TT * HD) + t * HD + hd] = acc;
    }
}

// MFMA score kernel. Block = 4 waves, one (s,i) head, 8 a's (2 per wave).
//   D[c,b] = sum_t (qa[t]*v[c,t]) * k[b,t]  via mfma_f32_32x32x16_f16.
// Row c=150 of V holds vbar = mean_c(v)/150  ->  D[150,b] = mean_c scores (free).
// C/D layout: col = lane&31, row = (reg&3) + 8*(reg>>2) + 4*(lane>>5).
// A layout:  A[m = lane&31][k = (lane>>5)*8 + j];  B[k][n = lane&31].
__global__ __launch_bounds__(256) void score_mfma_kernel(
    const float* __restrict__ q, const float* __restrict__ k, const float* __restrict__ v,
    float* __restrict__ attn) {
    int blk = blockIdx.x;            // [0, 1520)
    int s = blk / 760;
    int rem = blk % 760;
    int i = rem / 19;
    int g = rem % 19;
    int tid = threadIdx.x;
    int wv = tid >> 6, lane = tid & 63;
    int lo = lane & 31, hh = lane >> 5;

    const float* qb = q + ((size_t)s * NI + i) * (TT * HD);
    const float* kb = k + ((size_t)s * NI + i) * (TT * HD);
    const float* vb = v + ((size_t)s * NI + i) * (TT * HD);

    __shared__ float qs[TT * HD];
    __shared__ float ks[TT * HD];
    __shared__ float vs[(TT + 1) * HD];
    for (int idx = tid; idx < TT * HD; idx += 256) {
        qs[idx] = qb[idx];
        ks[idx] = kb[idx];
        vs[idx] = vb[idx];
    }
    __syncthreads();
    if (wv == 0) {   // vbar row (pre-scaled by 1/150) into vs row 150
        float v6[6] = {0.f, 0.f, 0.f, 0.f, 0.f, 0.f};
        for (int c = lane; c < TT; c += 64) {
            #pragma unroll
            for (int t = 0; t < 6; t++) v6[t] += vs[c * 6 + t];
        }
        #pragma unroll
        for (int m = 32; m > 0; m >>= 1) {
            #pragma unroll
            for (int t = 0; t < 6; t++) v6[t] += __shfl_xor(v6[t], m, 64);
        }
        if (lane < 6) vs[TT * 6 + lane] = v6[lane] * (1.f / TT);
    }
    __syncthreads();

    half8 bfrag[5], vhalf[5];
    #pragma unroll
    for (int nt = 0; nt < 5; nt++) {
        int rr = nt * 32 + lo;
        half8 bf; half8 vf;
        #pragma unroll
        for (int t = 0; t < 8; t++) { bf[t] = (_Float16)0.f; vf[t] = (_Float16)0.f; }
        if (hh == 0) {
            if (rr < TT) {
                #pragma unroll
                for (int t = 0; t < 6; t++) bf[t] = (_Float16)ks[rr * 6 + t];
            }
            if (rr <= TT) {   // includes the vbar row (c==150)
                #pragma unroll
                for (int t = 0; t < 6; t++) vf[t] = (_Float16)vs[rr * 6 + t];
            }
        }
        bfrag[nt] = bf; vhalf[nt] = vf;
    }

    f32x16 zacc;
    #pragma unroll
    for (int j = 0; j < 16; j++) zacc[j] = 0.f;

    for (int ap = 0; ap < 2; ap++) {
        int a = g * 8 + wv * 2 + ap;
        if (a >= TT) break;
        half8 qav;
        #pragma unroll
        for (int t = 0; t < 8; t++) qav[t] = (_Float16)((t < 6) ? qs[a * 6 + t] : 0.f);
        half8 afrag[5];
        #pragma unroll
        for (int nt = 0; nt < 5; nt++) afrag[nt] = vhalf[nt] * qav;  // v_pk_mul_f16

        float fsc[5];
        #pragma unroll
        for (int nb = 0; nb < 5; nb++) {
            float rm = -INFINITY;
            #pragma unroll
            for (int ma = 0; ma < 4; ma++) {
                f32x16 acc = __builtin_amdgcn_mfma_f32_32x32x16_f16(afrag[ma], bfrag[nb], zacc, 0, 0, 0);
                float m = fmaxf(acc[0], acc[1]);
                #pragma unroll
                for (int j = 2; j < 16; j += 2) m = fmaxf(fmaxf(m, acc[j]), acc[j + 1]);
                rm = fmaxf(rm, m);
            }
            f32x16 a4 = __builtin_amdgcn_mfma_f32_32x32x16_f16(afrag[4], bfrag[nb], zacc, 0, 0, 0);
            // live rows: h==0 -> regs 0..11 (c<=147); h==1 -> regs 0..9 (c<=149)
            float m4 = fmaxf(a4[0], a4[1]);
            #pragma unroll
            for (int j = 2; j < 10; j += 2) m4 = fmaxf(fmaxf(m4, a4[j]), a4[j + 1]);
            float ext = (hh == 0) ? fmaxf(a4[10], a4[11]) : -INFINITY;
            rm = fmaxf(rm, fmaxf(m4, ext));
            // mean at reg10 of h==1 lanes (row c==150 = vbar row)
            float om = __shfl_xor(a4[10], 32, 64);
            float mn = hh ? a4[10] : om;
            rm = fmaxf(rm, __shfl_xor(rm, 32, 64));
            int b = nb * 32 + lo;
            fsc[nb] = (b < TT) ? (mn + rm) : -INFINITY;
        }
        // softmax over b (32-lane groups each hold full b-range; halves duplicate)
        float m = fsc[0];
        #pragma unroll
        for (int nb = 1; nb < 5; nb++) m = fmaxf(m, fsc[nb]);
        #pragma unroll
        for (int msk = 16; msk > 0; msk >>= 1) m = fmaxf(m, __shfl_xor(m, msk, 64));
        float e[5], es = 0.f;
        #pragma unroll
        for (int nb = 0; nb < 5; nb++) { e[nb] = __expf(fsc[nb] - m); es += e[nb]; }
        #pragma unroll
        for (int msk = 16; msk > 0; msk >>= 1) es += __shfl_xor(es, msk, 64);
        // attn[a,:] = sum_b p_b * q[b,:]
        float acc6[6] = {0.f, 0.f, 0.f, 0.f, 0.f, 0.f};
        #pragma unroll
        for (int nb = 0; nb < 5; nb++) {
            int b = nb * 32 + lo;
            int bi = (b < TT) ? b : 0;
            float wgt = e[nb];
            #pragma unroll
            for (int t = 0; t < 6; t++) acc6[t] += wgt * qs[bi * 6 + t];
        }
        #pragma unroll
        for (int msk = 16; msk > 0; msk >>= 1) {
            #pragma unroll
            for (int t = 0; t < 6; t++) acc6[t] += __shfl_xor(acc6[t], msk, 64);
        }
        if (lane == 0) {
            float inv = 1.f / es;
            int bo = i / HH, ho = i % HH;
            float* dst = attn + (size_t)s * ROWF + a * (BB * DD) + bo * DD + ho * HD;
            #pragma unroll
            for (int t = 0; t < 6; t++) dst[t] = acc6[t] * inv;
        }
    }
}

// One wave per (s,tb); 4 waves/block. x1 = res + attn@ow.T + ob; h = x1 + FFN(LN(x1))
__global__ __launch_bounds__(256) void outffn_kernel(
    const float* __restrict__ attn, const float* __restrict__ pl,
    const float* __restrict__ out_w, const float* __restrict__ out_b,
    const float* __restrict__ l1w, const float* __restrict__ l1b,
    const float* __restrict__ l2w, const float* __restrict__ l2b,
    const float* __restrict__ n2g, const float* __restrict__ n2b, int l,
    float* __restrict__ h) {
    int w = threadIdx.x >> 6, lane = threadIdx.x & 63;
    int unit = blockIdx.x * 4 + w;          // [0,2400)
    int s = unit / 1200, tb = unit % 1200;
    int po = s * LL + l;
    const float* ow = out_w + (size_t)po * 900;
    const float* ob = out_b + (size_t)po * 30;
    const float* w1 = l1w + (size_t)po * 120 * 30;
    const float* b1 = l1b + (size_t)po * 120;
    const float* w2 = l2w + (size_t)po * 30 * 120;
    const float* b2 = l2b + (size_t)po * 30;
    const float* g  = n2g + (size_t)po * 30;
    const float* bbv = n2b + (size_t)po * 30;
    float* hrow = h + (size_t)s * ROWF + (size_t)tb * 30;
    const float* res = (l == 0) ? (pl + (size_t)tb * 30) : hrow;
    const float* arow = attn + (size_t)s * ROWF + (size_t)tb * 30;
    __shared__ float ar[4][30], x1[4][30], xn[4][30], hid[4][120];
    if (lane < 30) ar[w][lane] = arow[lane];
    __syncthreads();
    float x1v = 0.f;
    if (lane < 30) {
        const float* wr = ow + lane * 30;
        float acc = 0.f;
        #pragma unroll 6
        for (int j = 0; j < 30; j++) acc += wr[j] * ar[w][j];
        x1v = res[lane] + acc + ob[lane];
        x1[w][lane] = x1v;
    }
    float mean = wsum(x1v) * (1.f / 30.f);
    float dv = (lane < 30) ? (x1v - mean) : 0.f;
    float var = wsum(dv * dv) * (1.f / 30.f);
    float inv = rsqrtf(var + 1e-5f);
    if (lane < 30) xn[w][lane] = dv * inv * g[lane] + bbv[lane];
    __syncthreads();
    for (int o = lane; o < 120; o += 64) {
        const float* wr = w1 + o * 30;
        float acc = 0.f;
        #pragma unroll 6
        for (int j = 0; j < 30; j++) acc += wr[j] * xn[w][j];
        hid[w][o] = fmaxf(acc + b1[o], 0.f);
    }
    __syncthreads();
    if (lane < 30) {
        const float* wr = w2 + lane * 120;
        float acc = 0.f;
        #pragma unroll 8
        for (int j = 0; j < 120; j++) acc += wr[j] * hid[w][j];
        hrow[lane] = x1[w][lane] + acc + b2[lane];
    }
}

// Final head: last_hs, proj MLP + residual, scalar out. Writes all 488 outputs.
__global__ __launch_bounds__(256) void head_kernel(
    const float* __restrict__ h,
    const float* __restrict__ p1w, const float* __restrict__ p1b,
    const float* __restrict__ p2w, const float* __restrict__ p2b,
    const float* __restrict__ ow, const float* __restrict__ ob,
    float* __restrict__ out) {
    int tid = threadIdx.x;
    __shared__ float lh[480], hid[480], pr[480];
    for (int idx = tid; idx < 480; idx += 256) {
        int b = idx / 60, j = idx % 60;
        int s = j / 30, d = j % 30;
        float vv = h[(size_t)s * ROWF + 149 * (BB * DD) + b * DD + d];
        lh[idx] = vv;
        out[8 + idx] = vv;   // last_hs output
    }
    __syncthreads();
    for (int idx = tid; idx < 480; idx += 256) {
        int b = idx / 60, o = idx % 60;
        const float* wr = p1w + o * 60;
        float acc = p1b[o];
        for (int j = 0; j < 60; j++) acc += wr[j] * lh[b * 60 + j];
        hid[idx] = fmaxf(acc, 0.f);
    }
    __syncthreads();
    for (int idx = tid; idx < 480; idx += 256) {
        int b = idx / 60, d = idx % 60;
        const float* wr = p2w + d * 60;
        float acc = p2b[d];
        for (int j = 0; j < 60; j++) acc += wr[j] * hid[b * 60 + j];
        pr[idx] = acc + lh[idx];
    }
    __syncthreads();
    if (tid < 8) {
        float acc = ob[0];
        for (int j = 0; j < 60; j++) acc += pr[tid * 60 + j] * ow[j];
        out[tid] = acc;     // out output
    }
}

extern "C" void kernel_launch(void* const* d_in, const int* in_sizes, int n_in,
                              void* d_out, int out_size, void* d_ws, size_t ws_size,
                              hipStream_t stream) {
    const float* x_l   = (const float*)d_in[0];
    const float* x_a   = (const float*)d_in[1];
    const float* x_v   = (const float*)d_in[2];
    const float* Wl    = (const float*)d_in[3];
    const float* Wa    = (const float*)d_in[4];
    const float* Wv    = (const float*)d_in[5];
    const float* in_w  = (const float*)d_in[6];
    const float* in_b  = (const float*)d_in[7];
    const float* out_w = (const float*)d_in[8];
    const float* out_b = (const float*)d_in[9];
    const float* l1w   = (const float*)d_in[10];
    const float* l1b   = (const float*)d_in[11];
    const float* l2w   = (const float*)d_in[12];
    const float* l2b   = (const float*)d_in[13];
    const float* n1g   = (const float*)d_in[14];
    const float* n1b   = (const float*)d_in[15];
    const float* n2g   = (const float*)d_in[16];
    const float* n2b   = (const float*)d_in[17];
    const float* p1w   = (const float*)d_in[18];
    const float* p1b   = (const float*)d_in[19];
    const float* p2w   = (const float*)d_in[20];
    const float* p2b   = (const float*)d_in[21];
    const float* oww   = (const float*)d_in[22];
    const float* obb   = (const float*)d_in[23];

    float* ws = (float*)d_ws;
    float* pl = ws;                   // 36000
    float* pa = ws + 36000;           // 36000
    float* pv = ws + 72000;           // 36000
    float* h  = ws + 108000;          // 72000 ([2][T][B][D])
    float* q  = ws + 180000;          // 72000 ([2][40][150][6])
    float* kk = ws + 252000;          // 72000
    float* vv = ws + 324000;          // 72000
    float* at = ws + 396000;          // 72000

    proj_kernel<<<300, 256, 0, stream>>>(x_l, Wl, pl, 300);
    proj_kernel<<<300, 256, 0, stream>>>(x_a, Wa, pa, 74);
    proj_kernel<<<300, 256, 0, stream>>>(x_v, Wv, pv, 35);

    for (int l = 0; l < LL; l++) {
        lnqkv_kernel<<<600, 256, 0, stream>>>(h, pl, pa, pv, in_w, in_b, n1g, n1b, l, q, kk, vv);
        score_mfma_kernel<<<1520, 256, 0, stream>>>(q, kk, vv, at);
        outffn_kernel<<<600, 256, 0, stream>>>(at, pl, out_w, out_b, l1w, l1b, l2w, l2b,
                                               n2g, n2b, l, h);
    }
    head_kernel<<<1, 256, 0, stream>>>(h, p1w, p1b, p2w, p2b, oww, obb, (float*)d_out);
}

// Round 4
// 280.404 us; speedup vs baseline: 1.7167x; 1.0100x over previous
//
#include <hip/hip_runtime.h>
#include <math.h>

// Model dims
#define BB 8
#define TT 150
#define DD 30
#define HH 5
#define HD 6
#define LL 3
#define NI 40            // B*H heads per stream
#define ROWF (TT*BB*DD)  // 36000 floats per [T,B,D] buffer
#define RSTR 8           // padded LDS row stride in halves (16B -> ds_read_b128)
#define NR 152           // padded row count (150 data + vbar + zero)

typedef _Float16 half8 __attribute__((ext_vector_type(8)));
typedef float f32x16 __attribute__((ext_vector_type(16)));

__device__ __forceinline__ float wsum(float v) {
    #pragma unroll
    for (int m = 32; m > 0; m >>= 1) v += __shfl_xor(v, m, 64);
    return v;
}

// All three k=1 conv projections in one launch. unit = which*1200 + t*8 + b.
__global__ __launch_bounds__(256) void proj3_kernel(
    const float* __restrict__ x_l, const float* __restrict__ x_a, const float* __restrict__ x_v,
    const float* __restrict__ Wl, const float* __restrict__ Wa, const float* __restrict__ Wv,
    float* __restrict__ pl, float* __restrict__ pa, float* __restrict__ pv) {
    int w = threadIdx.x >> 6, lane = threadIdx.x & 63;
    int unit = blockIdx.x * 4 + w;          // [0,3600)
    int which = unit / 1200, rowu = unit % 1200;
    int t = rowu / BB, b = rowu % BB;
    const float* x = which == 0 ? x_l : (which == 1 ? x_a : x_v);
    const float* W = which == 0 ? Wl : (which == 1 ? Wa : Wv);
    float* out = which == 0 ? pl : (which == 1 ? pa : pv);
    int Cin = which == 0 ? 300 : (which == 1 ? 74 : 35);
    __shared__ float xr[4][304];
    const float* xp = x + ((size_t)b * TT + t) * Cin;
    for (int j = lane; j < Cin; j += 64) xr[w][j] = xp[j];
    __syncthreads();
    int d = lane >> 1, jh = lane & 1;
    int h1 = Cin >> 1;
    int j0 = jh ? h1 : 0, j1 = jh ? Cin : h1;
    const float* wr = W + (size_t)(d < DD ? d : 0) * Cin;
    float acc = 0.f;
    for (int j = j0; j < j1; j++) acc += xr[w][j] * wr[j];
    acc += __shfl_xor(acc, 1, 64);
    if (jh == 0 && d < DD) out[t * (BB * DD) + b * DD + d] = acc;
}

// One wave per (s,tb); 4 waves/block. LN rows, project to q/k/v head layout.
__global__ __launch_bounds__(256) void lnqkv_kernel(
    const float* __restrict__ h, const float* __restrict__ pl,
    const float* __restrict__ pa, const float* __restrict__ pv,
    const float* __restrict__ in_w, const float* __restrict__ in_b,
    const float* __restrict__ n1g, const float* __restrict__ n1b, int l,
    float* __restrict__ q, float* __restrict__ k, float* __restrict__ v) {
    int w = threadIdx.x >> 6, lane = threadIdx.x & 63;
    int unit = blockIdx.x * 4 + w;          // [0,2400)
    int s = unit / 1200, tb = unit % 1200;
    int t = tb / BB, b = tb % BB;
    const float* xk = (s == 0) ? pa : pv;
    const float* xv = (s == 0) ? pv : pa;
    int po = s * LL + l;
    const float* iw = in_w + (size_t)po * 90 * 30;
    const float* ib = in_b + (size_t)po * 90;
    const float* g  = n1g + (size_t)po * 30;
    const float* bbv = n1b + (size_t)po * 30;
    __shared__ float xn[4][3][30];
    const float* rows[3];
    rows[0] = (l == 0) ? (pl + (size_t)tb * 30) : (h + (size_t)s * ROWF + (size_t)tb * 30);
    rows[1] = xk + (size_t)tb * 30;
    rows[2] = xv + (size_t)tb * 30;
    for (int r = 0; r < 3; r++) {
        float xval = (lane < 30) ? rows[r][lane] : 0.f;
        float mean = wsum(xval) * (1.f / 30.f);
        float dv = (lane < 30) ? (xval - mean) : 0.f;
        float var = wsum(dv * dv) * (1.f / 30.f);
        float inv = rsqrtf(var + 1e-5f);
        if (lane < 30) xn[w][r][lane] = dv * inv * g[lane] + bbv[lane];
    }
    __syncthreads();
    for (int o = lane; o < 90; o += 64) {
        int which = o / 30, dd = o % 30;
        const float* wr = iw + o * 30;
        const float* xr = xn[w][which];
        float acc = 0.f;
        #pragma unroll 6
        for (int j = 0; j < 30; j++) acc += wr[j] * xr[j];
        acc += ib[o];
        if (which == 0) acc *= 0.40824829046386307f;  // HD^-0.5
        int i = b * HH + dd / HD, hd = dd % HD;
        float* dst = (which == 0) ? q : ((which == 1) ? k : v);
        dst[((size_t)s * NI + i) * (TT * HD) + t * HD + hd] = acc;
    }
}

// Fused score + out-proj + FFN. Block = (s, b, g): stages all 5 heads of batch b
// as f16 in LDS, each wave owns a = g*4+wv, loops over heads computing
// fused scores via mfma_f32_32x32x16_f16 (vbar row c=150 provides the mean),
// softmax, attn = sum_b p*q -> per-wave LDS row; then FFN for row (t=a, b).
// C/D layout: col = lane&31, row = (reg&3) + 8*(reg>>2) + 4*(lane>>5).
__global__ __launch_bounds__(256) void scoreffn_kernel(
    const float* __restrict__ q, const float* __restrict__ k, const float* __restrict__ v,
    const float* __restrict__ pl,
    const float* __restrict__ out_w, const float* __restrict__ out_b,
    const float* __restrict__ l1w, const float* __restrict__ l1b,
    const float* __restrict__ l2w, const float* __restrict__ l2b,
    const float* __restrict__ n2g, const float* __restrict__ n2b, int l,
    float* __restrict__ h) {
    int blk = blockIdx.x;                   // [0, 608)
    int s = blk / 304;
    int rem = blk % 304;
    int b = rem / 38;
    int g = rem % 38;
    int tid = threadIdx.x;
    int wv = tid >> 6, lane = tid & 63;
    int lo = lane & 31, hf = lane >> 5;

    __shared__ __align__(16) _Float16 qsh[HH][NR * RSTR];
    __shared__ __align__(16) _Float16 ksh[HH][NR * RSTR];
    __shared__ __align__(16) _Float16 vsh[HH][NR * RSTR];
    __shared__ float attnS[4][32];
    __shared__ float xnS[4][32];
    __shared__ float hidS[4][128];

    // zero-fill staging (covers pad cols 6..7 and pad rows 150..151)
    int* qz = (int*)&qsh[0][0];
    int* kz = (int*)&ksh[0][0];
    int* vz = (int*)&vsh[0][0];
    for (int idx = tid; idx < HH * NR * RSTR / 2; idx += 256) {
        qz[idx] = 0; kz[idx] = 0; vz[idx] = 0;
    }
    __syncthreads();
    // fill from global (fp32 -> f16); global head blocks are contiguous
    const float* qg = q + (size_t)(s * NI + b * HH) * (TT * HD);
    const float* kg = k + (size_t)(s * NI + b * HH) * (TT * HD);
    const float* vg = v + (size_t)(s * NI + b * HH) * (TT * HD);
    for (int idx = tid; idx < HH * TT * HD; idx += 256) {
        int h5 = idx / (TT * HD);
        int rr = (idx % (TT * HD)) / HD;
        int t = idx % HD;
        int dst = rr * RSTR + t;
        qsh[h5][dst] = (_Float16)qg[idx];
        ksh[h5][dst] = (_Float16)kg[idx];
        vsh[h5][dst] = (_Float16)vg[idx];
    }
    __syncthreads();
    // vbar row (pre-scaled by 1/150) into vsh row 150, per head
    for (int h5 = wv; h5 < HH; h5 += 4) {
        float v6[6] = {0.f, 0.f, 0.f, 0.f, 0.f, 0.f};
        for (int c = lane; c < TT; c += 64) {
            #pragma unroll
            for (int t = 0; t < 6; t++) v6[t] += (float)vsh[h5][c * RSTR + t];
        }
        #pragma unroll
        for (int m = 32; m > 0; m >>= 1) {
            #pragma unroll
            for (int t = 0; t < 6; t++) v6[t] += __shfl_xor(v6[t], m, 64);
        }
        if (lane < 6) vsh[h5][TT * RSTR + lane] = (_Float16)(v6[lane] * (1.f / TT));
    }
    __syncthreads();

    int a = g * 4 + wv;
    bool alive = (a < TT);

    f32x16 zacc;
    #pragma unroll
    for (int j = 0; j < 16; j++) zacc[j] = 0.f;
    half8 zero8;
    #pragma unroll
    for (int t = 0; t < 8; t++) zero8[t] = (_Float16)0.f;

    if (alive) {
        for (int h5 = 0; h5 < HH; h5++) {
            const _Float16* kbase = qsh[0];  // placeholder to keep types; real below
            (void)kbase;
            half8 qav = *(const half8*)&qsh[h5][a * RSTR];
            half8 bfrag[5], afrag[5];
            #pragma unroll
            for (int nt = 0; nt < 5; nt++) {
                int rr = nt * 32 + lo;
                int rc = rr < 151 ? rr : 151;      // rows 150/151: k=0, v=vbar/0
                half8 kf = *(const half8*)&ksh[h5][rc * RSTR];
                half8 vf = *(const half8*)&vsh[h5][rc * RSTR];
                bfrag[nt] = hf ? zero8 : kf;
                afrag[nt] = hf ? zero8 : (vf * qav);
            }
            float fsc[5];
            #pragma unroll
            for (int nb = 0; nb < 5; nb++) {
                float rm = -INFINITY;
                #pragma unroll
                for (int ma = 0; ma < 4; ma++) {
                    f32x16 acc = __builtin_amdgcn_mfma_f32_32x32x16_f16(afrag[ma], bfrag[nb], zacc, 0, 0, 0);
                    float m = fmaxf(acc[0], acc[1]);
                    #pragma unroll
                    for (int j = 2; j < 16; j += 2) m = fmaxf(fmaxf(m, acc[j]), acc[j + 1]);
                    rm = fmaxf(rm, m);
                }
                f32x16 a4 = __builtin_amdgcn_mfma_f32_32x32x16_f16(afrag[4], bfrag[nb], zacc, 0, 0, 0);
                // live rows: hf==0 -> regs 0..11 (c<=147); hf==1 -> regs 0..9 (c<=149)
                float m4 = fmaxf(a4[0], a4[1]);
                #pragma unroll
                for (int j = 2; j < 10; j += 2) m4 = fmaxf(fmaxf(m4, a4[j]), a4[j + 1]);
                float ext = (hf == 0) ? fmaxf(a4[10], a4[11]) : -INFINITY;
                rm = fmaxf(rm, fmaxf(m4, ext));
                // mean sits at reg10 of hf==1 lanes (row c==150 = vbar row)
                float om = __shfl_xor(a4[10], 32, 64);
                float mn = hf ? a4[10] : om;
                rm = fmaxf(rm, __shfl_xor(rm, 32, 64));
                int bcol = nb * 32 + lo;
                fsc[nb] = (bcol < TT) ? (mn + rm) : -INFINITY;
            }
            // softmax over b within each 32-lane group (halves duplicate)
            float m = fsc[0];
            #pragma unroll
            for (int nb = 1; nb < 5; nb++) m = fmaxf(m, fsc[nb]);
            #pragma unroll
            for (int msk = 16; msk > 0; msk >>= 1) m = fmaxf(m, __shfl_xor(m, msk, 64));
            float e[5], es = 0.f;
            #pragma unroll
            for (int nb = 0; nb < 5; nb++) { e[nb] = __expf(fsc[nb] - m); es += e[nb]; }
            #pragma unroll
            for (int msk = 16; msk > 0; msk >>= 1) es += __shfl_xor(es, msk, 64);
            // attn[a,:] = sum_b p_b * q[b,:]
            float acc6[6] = {0.f, 0.f, 0.f, 0.f, 0.f, 0.f};
            #pragma unroll
            for (int nb = 0; nb < 5; nb++) {
                int bcol = nb * 32 + lo;
                int bi = (bcol < TT) ? bcol : 0;
                float wgt = e[nb];
                half8 qrow = *(const half8*)&qsh[h5][bi * RSTR];
                #pragma unroll
                for (int t = 0; t < 6; t++) acc6[t] += wgt * (float)qrow[t];
            }
            #pragma unroll
            for (int msk = 16; msk > 0; msk >>= 1) {
                #pragma unroll
                for (int t = 0; t < 6; t++) acc6[t] += __shfl_xor(acc6[t], msk, 64);
            }
            if (lane == 0) {
                float inv = 1.f / es;
                #pragma unroll
                for (int t = 0; t < 6; t++) attnS[wv][h5 * 6 + t] = acc6[t] * inv;
            }
        }

        // ---- FFN for row (t = a, b); all scratch is wave-private ----
        int tb = a * BB + b;
        int po = s * LL + l;
        const float* ow = out_w + (size_t)po * 900;
        const float* ob = out_b + (size_t)po * 30;
        const float* w1 = l1w + (size_t)po * 120 * 30;
        const float* b1 = l1b + (size_t)po * 120;
        const float* w2 = l2w + (size_t)po * 30 * 120;
        const float* b2 = l2b + (size_t)po * 30;
        const float* gg = n2g + (size_t)po * 30;
        const float* bbv = n2b + (size_t)po * 30;
        float* hrow = h + (size_t)s * ROWF + (size_t)tb * 30;
        const float* res = (l == 0) ? (pl + (size_t)tb * 30) : hrow;
        float x1v = 0.f;
        if (lane < 30) {
            const float* wr = ow + lane * 30;
            float acc = 0.f;
            #pragma unroll 6
            for (int j = 0; j < 30; j++) acc += wr[j] * attnS[wv][j];
            x1v = res[lane] + acc + ob[lane];
        }
        float mean = wsum(x1v) * (1.f / 30.f);
        float dv = (lane < 30) ? (x1v - mean) : 0.f;
        float var = wsum(dv * dv) * (1.f / 30.f);
        float inv = rsqrtf(var + 1e-5f);
        if (lane < 30) xnS[wv][lane] = dv * inv * gg[lane] + bbv[lane];
        for (int o = lane; o < 120; o += 64) {
            const float* wr = w1 + o * 30;
            float acc = 0.f;
            #pragma unroll 6
            for (int j = 0; j < 30; j++) acc += wr[j] * xnS[wv][j];
            hidS[wv][o] = fmaxf(acc + b1[o], 0.f);
        }
        if (lane < 30) {
            const float* wr = w2 + lane * 120;
            float acc = 0.f;
            #pragma unroll 8
            for (int j = 0; j < 120; j++) acc += wr[j] * hidS[wv][j];
            hrow[lane] = x1v + acc + b2[lane];
        }
    }
}

// Final head: last_hs, proj MLP + residual, scalar out. Writes all 488 outputs.
__global__ __launch_bounds__(256) void head_kernel(
    const float* __restrict__ h,
    const float* __restrict__ p1w, const float* __restrict__ p1b,
    const float* __restrict__ p2w, const float* __restrict__ p2b,
    const float* __restrict__ ow, const float* __restrict__ ob,
    float* __restrict__ out) {
    int tid = threadIdx.x;
    __shared__ float lh[480], hid[480], pr[480];
    for (int idx = tid; idx < 480; idx += 256) {
        int b = idx / 60, j = idx % 60;
        int s = j / 30, d = j % 30;
        float vv = h[(size_t)s * ROWF + 149 * (BB * DD) + b * DD + d];
        lh[idx] = vv;
        out[8 + idx] = vv;   // last_hs output
    }
    __syncthreads();
    for (int idx = tid; idx < 480; idx += 256) {
        int b = idx / 60, o = idx % 60;
        const float* wr = p1w + o * 60;
        float acc = p1b[o];
        for (int j = 0; j < 60; j++) acc += wr[j] * lh[b * 60 + j];
        hid[idx] = fmaxf(acc, 0.f);
    }
    __syncthreads();
    for (int idx = tid; idx < 480; idx += 256) {
        int b = idx / 60, d = idx % 60;
        const float* wr = p2w + d * 60;
        float acc = p2b[d];
        for (int j = 0; j < 60; j++) acc += wr[j] * hid[b * 60 + j];
        pr[idx] = acc + lh[idx];
    }
    __syncthreads();
    if (tid < 8) {
        float acc = ob[0];
        for (int j = 0; j < 60; j++) acc += pr[tid * 60 + j] * ow[j];
        out[tid] = acc;     // out output
    }
}

extern "C" void kernel_launch(void* const* d_in, const int* in_sizes, int n_in,
                              void* d_out, int out_size, void* d_ws, size_t ws_size,
                              hipStream_t stream) {
    const float* x_l   = (const float*)d_in[0];
    const float* x_a   = (const float*)d_in[1];
    const float* x_v   = (const float*)d_in[2];
    const float* Wl    = (const float*)d_in[3];
    const float* Wa    = (const float*)d_in[4];
    const float* Wv    = (const float*)d_in[5];
    const float* in_w  = (const float*)d_in[6];
    const float* in_b  = (const float*)d_in[7];
    const float* out_w = (const float*)d_in[8];
    const float* out_b = (const float*)d_in[9];
    const float* l1w   = (const float*)d_in[10];
    const float* l1b   = (const float*)d_in[11];
    const float* l2w   = (const float*)d_in[12];
    const float* l2b   = (const float*)d_in[13];
    const float* n1g   = (const float*)d_in[14];
    const float* n1b   = (const float*)d_in[15];
    const float* n2g   = (const float*)d_in[16];
    const float* n2b   = (const float*)d_in[17];
    const float* p1w   = (const float*)d_in[18];
    const float* p1b   = (const float*)d_in[19];
    const float* p2w   = (const float*)d_in[20];
    const float* p2b   = (const float*)d_in[21];
    const float* oww   = (const float*)d_in[22];
    const float* obb   = (const float*)d_in[23];

    float* ws = (float*)d_ws;
    float* pl = ws;                   // 36000
    float* pa = ws + 36000;           // 36000
    float* pv = ws + 72000;           // 36000
    float* h  = ws + 108000;          // 72000 ([2][T][B][D])
    float* q  = ws + 180000;          // 72000 ([2][40][150][6])
    float* kk = ws + 252000;          // 72000
    float* vv = ws + 324000;          // 72000

    proj3_kernel<<<900, 256, 0, stream>>>(x_l, x_a, x_v, Wl, Wa, Wv, pl, pa, pv);

    for (int l = 0; l < LL; l++) {
        lnqkv_kernel<<<600, 256, 0, stream>>>(h, pl, pa, pv, in_w, in_b, n1g, n1b, l, q, kk, vv);
        scoreffn_kernel<<<608, 256, 0, stream>>>(q, kk, vv, pl, out_w, out_b,
                                                 l1w, l1b, l2w, l2b, n2g, n2b, l, h);
    }
    head_kernel<<<1, 256, 0, stream>>>(h, p1w, p1b, p2w, p2b, oww, obb, (float*)d_out);
}

// Round 5
// 261.431 us; speedup vs baseline: 1.8413x; 1.0726x over previous
//
#include <hip/hip_runtime.h>
#include <math.h>

// Model dims
#define BB 8
#define TT 150
#define DD 30
#define HH 5
#define HD 6
#define LL 3
#define NI 40            // B*H heads per stream
#define ROWF (TT*BB*DD)  // 36000 floats per [T,B,D] buffer
#define RSTR 8           // padded LDS row stride in halves (16B -> ds_read_b128)
#define NR 152           // padded row count (150 data + vbar + zero)

typedef _Float16 half8 __attribute__((ext_vector_type(8)));
typedef float f32x16 __attribute__((ext_vector_type(16)));

__device__ __forceinline__ float wsum(float v) {
    #pragma unroll
    for (int m = 32; m > 0; m >>= 1) v += __shfl_xor(v, m, 64);
    return v;
}

// All three k=1 conv projections. 300 blocks per input; weights staged in LDS.
__global__ __launch_bounds__(256) void proj3_kernel(
    const float* __restrict__ x_l, const float* __restrict__ x_a, const float* __restrict__ x_v,
    const float* __restrict__ Wl, const float* __restrict__ Wa, const float* __restrict__ Wv,
    float* __restrict__ pl, float* __restrict__ pa, float* __restrict__ pv) {
    int blk = blockIdx.x;                   // [0,900)
    int which = blk / 300;
    int w = threadIdx.x >> 6, lane = threadIdx.x & 63;
    int rowu = (blk % 300) * 4 + w;         // [0,1200)
    int t = rowu / BB, b = rowu % BB;
    const float* x = which == 0 ? x_l : (which == 1 ? x_a : x_v);
    const float* W = which == 0 ? Wl : (which == 1 ? Wa : Wv);
    float* out = which == 0 ? pl : (which == 1 ? pa : pv);
    int Cin = which == 0 ? 300 : (which == 1 ? 74 : 35);
    int cst = Cin + ((Cin & 1) ? 0 : 1);    // odd LDS row stride -> bank spread
    __shared__ float WS[30 * 301];
    __shared__ float xr[4][304];
    for (int j = threadIdx.x; j < DD * Cin; j += 256)
        WS[(j / Cin) * cst + (j % Cin)] = W[j];
    const float* xp = x + ((size_t)b * TT + t) * Cin;
    for (int j = lane; j < Cin; j += 64) xr[w][j] = xp[j];
    __syncthreads();
    int d = lane >> 1, jh = lane & 1;
    int h1 = Cin >> 1;
    int j0 = jh ? h1 : 0, j1 = jh ? Cin : h1;
    const float* wr = WS + (size_t)(d < DD ? d : 0) * cst;
    float acc = 0.f;
    for (int j = j0; j < j1; j++) acc += xr[w][j] * wr[j];
    acc += __shfl_xor(acc, 1, 64);
    if (jh == 0 && d < DD) out[t * (BB * DD) + b * DD + d] = acc;
}

// One wave per tb; 4 waves/block; block-uniform (s,l) weights staged in LDS.
__global__ __launch_bounds__(256) void lnqkv_kernel(
    const float* __restrict__ h, const float* __restrict__ pl,
    const float* __restrict__ pa, const float* __restrict__ pv,
    const float* __restrict__ in_w, const float* __restrict__ in_b,
    const float* __restrict__ n1g, const float* __restrict__ n1b, int l,
    float* __restrict__ q, float* __restrict__ k, float* __restrict__ v) {
    int blk = blockIdx.x;                   // [0,600)
    int s = blk / 300;
    int w = threadIdx.x >> 6, lane = threadIdx.x & 63;
    int tb = (blk % 300) * 4 + w;           // [0,1200)
    int t = tb / BB, b = tb % BB;
    const float* xk = (s == 0) ? pa : pv;
    const float* xv = (s == 0) ? pv : pa;
    int po = s * LL + l;
    const float* iw = in_w + (size_t)po * 90 * 30;
    const float* ib = in_b + (size_t)po * 90;
    const float* g  = n1g + (size_t)po * 30;
    const float* bbv = n1b + (size_t)po * 30;
    __shared__ float iwS[2700];
    __shared__ float xn[4][3][30];
    for (int j = threadIdx.x; j < 2700; j += 256) iwS[j] = iw[j];
    const float* rows[3];
    rows[0] = (l == 0) ? (pl + (size_t)tb * 30) : (h + (size_t)s * ROWF + (size_t)tb * 30);
    rows[1] = xk + (size_t)tb * 30;
    rows[2] = xv + (size_t)tb * 30;
    for (int r = 0; r < 3; r++) {
        float xval = (lane < 30) ? rows[r][lane] : 0.f;
        float mean = wsum(xval) * (1.f / 30.f);
        float dv = (lane < 30) ? (xval - mean) : 0.f;
        float var = wsum(dv * dv) * (1.f / 30.f);
        float inv = rsqrtf(var + 1e-5f);
        if (lane < 30) xn[w][r][lane] = dv * inv * g[lane] + bbv[lane];
    }
    __syncthreads();
    for (int o = lane; o < 90; o += 64) {
        int which = o / 30, dd = o % 30;
        const float* wr = iwS + o * 30;
        const float* xr = xn[w][which];
        float acc = 0.f;
        #pragma unroll 6
        for (int j = 0; j < 30; j++) acc += wr[j] * xr[j];
        acc += ib[o];
        if (which == 0) acc *= 0.40824829046386307f;  // HD^-0.5
        int i = b * HH + dd / HD, hd = dd % HD;
        float* dst = (which == 0) ? q : ((which == 1) ? k : v);
        dst[((size_t)s * NI + i) * (TT * HD) + t * HD + hd] = acc;
    }
}

// Score kernel: block = (s, head i, g); stages ONE head f16 in LDS (7.3 KB),
// 4 waves x 2 a's. Fused scores via mfma_f32_32x32x16_f16; vbar row c=150
// provides the mean for free; softmax; attn = sum_b p*q -> global.
// C/D layout: col = lane&31, row = (reg&3) + 8*(reg>>2) + 4*(lane>>5).
__global__ __launch_bounds__(256) void score_kernel(
    const float* __restrict__ q, const float* __restrict__ k, const float* __restrict__ v,
    float* __restrict__ attn) {
    int blk = blockIdx.x;                   // [0, 1520)
    int s = blk / 760;
    int rem = blk % 760;
    int i = rem / 19;
    int g = rem % 19;
    int tid = threadIdx.x;
    int wv = tid >> 6, lane = tid & 63;
    int lo = lane & 31, hf = lane >> 5;

    __shared__ __align__(16) _Float16 qsh[NR * RSTR];
    __shared__ __align__(16) _Float16 ksh[NR * RSTR];
    __shared__ __align__(16) _Float16 vsh[NR * RSTR];

    int* qz = (int*)qsh; int* kz = (int*)ksh; int* vz = (int*)vsh;
    for (int idx = tid; idx < NR * RSTR / 2; idx += 256) {
        qz[idx] = 0; kz[idx] = 0; vz[idx] = 0;
    }
    __syncthreads();
    const float* qg = q + (size_t)(s * NI + i) * (TT * HD);
    const float* kg = k + (size_t)(s * NI + i) * (TT * HD);
    const float* vg = v + (size_t)(s * NI + i) * (TT * HD);
    for (int idx = tid; idx < TT * HD; idx += 256) {
        int dst = (idx / HD) * RSTR + (idx % HD);
        qsh[dst] = (_Float16)qg[idx];
        ksh[dst] = (_Float16)kg[idx];
        vsh[dst] = (_Float16)vg[idx];
    }
    __syncthreads();
    if (wv == 0) {   // vbar row (pre-scaled by 1/150) into vsh row 150
        float v6[6] = {0.f, 0.f, 0.f, 0.f, 0.f, 0.f};
        for (int c = lane; c < TT; c += 64) {
            #pragma unroll
            for (int t = 0; t < 6; t++) v6[t] += (float)vsh[c * RSTR + t];
        }
        #pragma unroll
        for (int m = 32; m > 0; m >>= 1) {
            #pragma unroll
            for (int t = 0; t < 6; t++) v6[t] += __shfl_xor(v6[t], m, 64);
        }
        if (lane < 6) vsh[TT * RSTR + lane] = (_Float16)(v6[lane] * (1.f / TT));
    }
    __syncthreads();

    f32x16 zacc;
    #pragma unroll
    for (int j = 0; j < 16; j++) zacc[j] = 0.f;
    half8 zero8;
    #pragma unroll
    for (int t = 0; t < 8; t++) zero8[t] = (_Float16)0.f;

    // stage fragments once per wave (shared by both a's)
    half8 bfrag[5], vhalf[5];
    #pragma unroll
    for (int nt = 0; nt < 5; nt++) {
        int rr = nt * 32 + lo;
        int rc = rr < 151 ? rr : 151;          // 150 = vbar, 151 = zeros
        half8 kf = *(const half8*)&ksh[rc * RSTR];
        half8 vf = *(const half8*)&vsh[rc * RSTR];
        bfrag[nt] = hf ? zero8 : kf;
        vhalf[nt] = hf ? zero8 : vf;
    }

    for (int ap = 0; ap < 2; ap++) {
        int a = g * 8 + wv * 2 + ap;
        if (a >= TT) break;
        half8 qav = *(const half8*)&qsh[a * RSTR];
        half8 afrag[5];
        #pragma unroll
        for (int nt = 0; nt < 5; nt++) afrag[nt] = vhalf[nt] * qav;  // v_pk_mul_f16

        float fsc[5];
        #pragma unroll
        for (int nb = 0; nb < 5; nb++) {
            float rm = -INFINITY;
            #pragma unroll
            for (int ma = 0; ma < 4; ma++) {
                f32x16 acc = __builtin_amdgcn_mfma_f32_32x32x16_f16(afrag[ma], bfrag[nb], zacc, 0, 0, 0);
                float m = fmaxf(acc[0], acc[1]);
                #pragma unroll
                for (int j = 2; j < 16; j += 2) m = fmaxf(fmaxf(m, acc[j]), acc[j + 1]);
                rm = fmaxf(rm, m);
            }
            f32x16 a4 = __builtin_amdgcn_mfma_f32_32x32x16_f16(afrag[4], bfrag[nb], zacc, 0, 0, 0);
            // live rows: hf==0 -> regs 0..11 (c<=147); hf==1 -> regs 0..9 (c<=149)
            float m4 = fmaxf(a4[0], a4[1]);
            #pragma unroll
            for (int j = 2; j < 10; j += 2) m4 = fmaxf(fmaxf(m4, a4[j]), a4[j + 1]);
            float ext = (hf == 0) ? fmaxf(a4[10], a4[11]) : -INFINITY;
            rm = fmaxf(rm, fmaxf(m4, ext));
            // mean sits at reg10 of hf==1 lanes (row c==150 = vbar row)
            float om = __shfl_xor(a4[10], 32, 64);
            float mn = hf ? a4[10] : om;
            rm = fmaxf(rm, __shfl_xor(rm, 32, 64));
            int bcol = nb * 32 + lo;
            fsc[nb] = (bcol < TT) ? (mn + rm) : -INFINITY;
        }
        // softmax over b within each 32-lane group (halves duplicate)
        float m = fsc[0];
        #pragma unroll
        for (int nb = 1; nb < 5; nb++) m = fmaxf(m, fsc[nb]);
        #pragma unroll
        for (int msk = 16; msk > 0; msk >>= 1) m = fmaxf(m, __shfl_xor(m, msk, 64));
        float e[5], es = 0.f;
        #pragma unroll
        for (int nb = 0; nb < 5; nb++) { e[nb] = __expf(fsc[nb] - m); es += e[nb]; }
        #pragma unroll
        for (int msk = 16; msk > 0; msk >>= 1) es += __shfl_xor(es, msk, 64);
        // attn[a,:] = sum_b p_b * q[b,:]
        float acc6[6] = {0.f, 0.f, 0.f, 0.f, 0.f, 0.f};
        #pragma unroll
        for (int nb = 0; nb < 5; nb++) {
            int bcol = nb * 32 + lo;
            int bi = (bcol < TT) ? bcol : 0;
            float wgt = e[nb];
            half8 qrow = *(const half8*)&qsh[bi * RSTR];
            #pragma unroll
            for (int t = 0; t < 6; t++) acc6[t] += wgt * (float)qrow[t];
        }
        #pragma unroll
        for (int msk = 16; msk > 0; msk >>= 1) {
            #pragma unroll
            for (int t = 0; t < 6; t++) acc6[t] += __shfl_xor(acc6[t], msk, 64);
        }
        if (lane == 0) {
            float inv = 1.f / es;
            int bo = i / HH, ho = i % HH;
            float* dst = attn + (size_t)s * ROWF + a * (BB * DD) + bo * DD + ho * HD;
            #pragma unroll
            for (int t = 0; t < 6; t++) dst[t] = acc6[t] * inv;
        }
    }
}

// FFN: one wave per tb; 4 waves/block; block-uniform weights staged in LDS.
// x1 = res + attn@ow.T + ob; h = x1 + lin2(relu(lin1(LN(x1))))
__global__ __launch_bounds__(256) void ffn_kernel(
    const float* __restrict__ attn, const float* __restrict__ pl,
    const float* __restrict__ out_w, const float* __restrict__ out_b,
    const float* __restrict__ l1w, const float* __restrict__ l1b,
    const float* __restrict__ l2w, const float* __restrict__ l2b,
    const float* __restrict__ n2g, const float* __restrict__ n2b, int l,
    float* __restrict__ h) {
    int blk = blockIdx.x;                   // [0,600)
    int s = blk / 300;
    int w = threadIdx.x >> 6, lane = threadIdx.x & 63;
    int tb = (blk % 300) * 4 + w;           // [0,1200)
    int po = s * LL + l;
    const float* ow = out_w + (size_t)po * 900;
    const float* ob = out_b + (size_t)po * 30;
    const float* w1 = l1w + (size_t)po * 120 * 30;
    const float* b1 = l1b + (size_t)po * 120;
    const float* w2 = l2w + (size_t)po * 30 * 120;
    const float* b2 = l2b + (size_t)po * 30;
    const float* g  = n2g + (size_t)po * 30;
    const float* bbv = n2b + (size_t)po * 30;
    __shared__ float owS[900];
    __shared__ float w1S[3600];
    __shared__ float w2S[30 * 121];         // row stride 121 -> bank spread
    __shared__ float arS[4][30], xnS[4][32], hidS[4][120];
    for (int j = threadIdx.x; j < 900; j += 256) owS[j] = ow[j];
    for (int j = threadIdx.x; j < 3600; j += 256) w1S[j] = w1[j];
    for (int j = threadIdx.x; j < 3600; j += 256) w2S[(j / 120) * 121 + (j % 120)] = w2[j];
    __syncthreads();
    float* hrow = h + (size_t)s * ROWF + (size_t)tb * 30;
    const float* res = (l == 0) ? (pl + (size_t)tb * 30) : hrow;
    const float* arow = attn + (size_t)s * ROWF + (size_t)tb * 30;
    if (lane < 30) arS[w][lane] = arow[lane];
    float x1v = 0.f;
    if (lane < 30) {
        const float* wr = owS + lane * 30;
        float acc = 0.f;
        #pragma unroll 6
        for (int j = 0; j < 30; j++) acc += wr[j] * arS[w][j];
        x1v = res[lane] + acc + ob[lane];
    }
    float mean = wsum(x1v) * (1.f / 30.f);
    float dv = (lane < 30) ? (x1v - mean) : 0.f;
    float var = wsum(dv * dv) * (1.f / 30.f);
    float inv = rsqrtf(var + 1e-5f);
    if (lane < 30) xnS[w][lane] = dv * inv * g[lane] + bbv[lane];
    for (int o = lane; o < 120; o += 64) {
        const float* wr = w1S + o * 30;
        float acc = 0.f;
        #pragma unroll 6
        for (int j = 0; j < 30; j++) acc += wr[j] * xnS[w][j];
        hidS[w][o] = fmaxf(acc + b1[o], 0.f);
    }
    if (lane < 30) {
        const float* wr = w2S + lane * 121;
        float acc = 0.f;
        #pragma unroll 8
        for (int j = 0; j < 120; j++) acc += wr[j] * hidS[w][j];
        hrow[lane] = x1v + acc + b2[lane];
    }
}

// Final head: last_hs, proj MLP + residual, scalar out. Writes all 488 outputs.
__global__ __launch_bounds__(256) void head_kernel(
    const float* __restrict__ h,
    const float* __restrict__ p1w, const float* __restrict__ p1b,
    const float* __restrict__ p2w, const float* __restrict__ p2b,
    const float* __restrict__ ow, const float* __restrict__ ob,
    float* __restrict__ out) {
    int tid = threadIdx.x;
    __shared__ float lh[480], hid[480], pr[480];
    for (int idx = tid; idx < 480; idx += 256) {
        int b = idx / 60, j = idx % 60;
        int s = j / 30, d = j % 30;
        float vv = h[(size_t)s * ROWF + 149 * (BB * DD) + b * DD + d];
        lh[idx] = vv;
        out[8 + idx] = vv;   // last_hs output
    }
    __syncthreads();
    for (int idx = tid; idx < 480; idx += 256) {
        int b = idx / 60, o = idx % 60;
        const float* wr = p1w + o * 60;
        float acc = p1b[o];
        for (int j = 0; j < 60; j++) acc += wr[j] * lh[b * 60 + j];
        hid[idx] = fmaxf(acc, 0.f);
    }
    __syncthreads();
    for (int idx = tid; idx < 480; idx += 256) {
        int b = idx / 60, d = idx % 60;
        const float* wr = p2w + d * 60;
        float acc = p2b[d];
        for (int j = 0; j < 60; j++) acc += wr[j] * hid[b * 60 + j];
        pr[idx] = acc + lh[idx];
    }
    __syncthreads();
    if (tid < 8) {
        float acc = ob[0];
        for (int j = 0; j < 60; j++) acc += pr[tid * 60 + j] * ow[j];
        out[tid] = acc;     // out output
    }
}

extern "C" void kernel_launch(void* const* d_in, const int* in_sizes, int n_in,
                              void* d_out, int out_size, void* d_ws, size_t ws_size,
                              hipStream_t stream) {
    const float* x_l   = (const float*)d_in[0];
    const float* x_a   = (const float*)d_in[1];
    const float* x_v   = (const float*)d_in[2];
    const float* Wl    = (const float*)d_in[3];
    const float* Wa    = (const float*)d_in[4];
    const float* Wv    = (const float*)d_in[5];
    const float* in_w  = (const float*)d_in[6];
    const float* in_b  = (const float*)d_in[7];
    const float* out_w = (const float*)d_in[8];
    const float* out_b = (const float*)d_in[9];
    const float* l1w   = (const float*)d_in[10];
    const float* l1b   = (const float*)d_in[11];
    const float* l2w   = (const float*)d_in[12];
    const float* l2b   = (const float*)d_in[13];
    const float* n1g   = (const float*)d_in[14];
    const float* n1b   = (const float*)d_in[15];
    const float* n2g   = (const float*)d_in[16];
    const float* n2b   = (const float*)d_in[17];
    const float* p1w   = (const float*)d_in[18];
    const float* p1b   = (const float*)d_in[19];
    const float* p2w   = (const float*)d_in[20];
    const float* p2b   = (const float*)d_in[21];
    const float* oww   = (const float*)d_in[22];
    const float* obb   = (const float*)d_in[23];

    float* ws = (float*)d_ws;
    float* pl = ws;                   // 36000
    float* pa = ws + 36000;           // 36000
    float* pv = ws + 72000;           // 36000
    float* h  = ws + 108000;          // 72000 ([2][T][B][D])
    float* q  = ws + 180000;          // 72000 ([2][40][150][6])
    float* kk = ws + 252000;          // 72000
    float* vv = ws + 324000;          // 72000
    float* at = ws + 396000;          // 72000

    proj3_kernel<<<900, 256, 0, stream>>>(x_l, x_a, x_v, Wl, Wa, Wv, pl, pa, pv);

    for (int l = 0; l < LL; l++) {
        lnqkv_kernel<<<600, 256, 0, stream>>>(h, pl, pa, pv, in_w, in_b, n1g, n1b, l, q, kk, vv);
        score_kernel<<<1520, 256, 0, stream>>>(q, kk, vv, at);
        ffn_kernel<<<600, 256, 0, stream>>>(at, pl, out_w, out_b, l1w, l1b, l2w, l2b,
                                            n2g, n2b, l, h);
    }
    head_kernel<<<1, 256, 0, stream>>>(h, p1w, p1b, p2w, p2b, oww, obb, (float*)d_out);
}

// Round 6
// 254.231 us; speedup vs baseline: 1.8935x; 1.0283x over previous
//
#include <hip/hip_runtime.h>
#include <math.h>

// Model dims
#define BB 8
#define TT 150
#define DD 30
#define HH 5
#define HD 6
#define LL 3
#define NI 40            // B*H heads per stream
#define ROWF (TT*BB*DD)  // 36000 floats per [T,B,D] buffer
#define RSTR 8           // padded LDS row stride in halves (16B -> ds_read_b128)
#define NR 152           // padded row count (150 data + vbar + zero)

typedef _Float16 half8 __attribute__((ext_vector_type(8)));
typedef float f32x16 __attribute__((ext_vector_type(16)));

__device__ __forceinline__ float wsum(float v) {
    #pragma unroll
    for (int m = 32; m > 0; m >>= 1) v += __shfl_xor(v, m, 64);
    return v;
}

// All three k=1 conv projections. 300 blocks per input; weights staged in LDS.
__global__ __launch_bounds__(256) void proj3_kernel(
    const float* __restrict__ x_l, const float* __restrict__ x_a, const float* __restrict__ x_v,
    const float* __restrict__ Wl, const float* __restrict__ Wa, const float* __restrict__ Wv,
    float* __restrict__ pl, float* __restrict__ pa, float* __restrict__ pv) {
    int blk = blockIdx.x;                   // [0,900)
    int which = blk / 300;
    int w = threadIdx.x >> 6, lane = threadIdx.x & 63;
    int rowu = (blk % 300) * 4 + w;         // [0,1200)
    int t = rowu / BB, b = rowu % BB;
    const float* x = which == 0 ? x_l : (which == 1 ? x_a : x_v);
    const float* W = which == 0 ? Wl : (which == 1 ? Wa : Wv);
    float* out = which == 0 ? pl : (which == 1 ? pa : pv);
    int Cin = which == 0 ? 300 : (which == 1 ? 74 : 35);
    int cst = Cin + ((Cin & 1) ? 0 : 1);    // odd LDS row stride -> bank spread
    __shared__ float WS[30 * 301];
    __shared__ float xr[4][304];
    for (int j = threadIdx.x; j < DD * Cin; j += 256)
        WS[(j / Cin) * cst + (j % Cin)] = W[j];
    const float* xp = x + ((size_t)b * TT + t) * Cin;
    for (int j = lane; j < Cin; j += 64) xr[w][j] = xp[j];
    __syncthreads();
    int d = lane >> 1, jh = lane & 1;
    int h1 = Cin >> 1;
    int j0 = jh ? h1 : 0, j1 = jh ? Cin : h1;
    const float* wr = WS + (size_t)(d < DD ? d : 0) * cst;
    float acc = 0.f;
    for (int j = j0; j < j1; j++) acc += xr[w][j] * wr[j];
    acc += __shfl_xor(acc, 1, 64);
    if (jh == 0 && d < DD) out[t * (BB * DD) + b * DD + d] = acc;
}

// Precompute k,v for ALL (s,l) combos (they depend only on pa/pv, not h).
// Block = (po = s*LL+l, 4 tb rows). k_all/v_all: [6][NI][TT][HD].
__global__ __launch_bounds__(256) void kvpre_kernel(
    const float* __restrict__ pa, const float* __restrict__ pv,
    const float* __restrict__ in_w, const float* __restrict__ in_b,
    const float* __restrict__ n1g, const float* __restrict__ n1b,
    float* __restrict__ k_all, float* __restrict__ v_all) {
    int blk = blockIdx.x;                   // [0,1800)
    int po = blk / 300;                     // s*LL+l
    int s = po / LL;
    int w = threadIdx.x >> 6, lane = threadIdx.x & 63;
    int tb = (blk % 300) * 4 + w;           // [0,1200)
    int t = tb / BB, b = tb % BB;
    const float* xk = (s == 0) ? pa : pv;
    const float* xv = (s == 0) ? pv : pa;
    const float* iw = in_w + (size_t)po * 2700 + 900;   // rows 30..89
    const float* ib = in_b + (size_t)po * 90;
    const float* g  = n1g + (size_t)po * 30;
    const float* bb = n1b + (size_t)po * 30;
    __shared__ float iwS[1800];
    __shared__ float xn[4][2][30];
    for (int j = threadIdx.x; j < 1800; j += 256) iwS[j] = iw[j];
    const float* rows[2] = { xk + (size_t)tb * 30, xv + (size_t)tb * 30 };
    for (int r = 0; r < 2; r++) {
        float xval = (lane < 30) ? rows[r][lane] : 0.f;
        float mean = wsum(xval) * (1.f / 30.f);
        float dv = (lane < 30) ? (xval - mean) : 0.f;
        float var = wsum(dv * dv) * (1.f / 30.f);
        float inv = rsqrtf(var + 1e-5f);
        if (lane < 30) xn[w][r][lane] = dv * inv * g[lane] + bb[lane];
    }
    __syncthreads();
    int o = lane;
    if (o < 60) {
        int which = o / 30, dd = o % 30;
        const float* wr = iwS + o * 30;
        const float* xr = xn[w][which];
        float acc = 0.f;
        #pragma unroll 6
        for (int j = 0; j < 30; j++) acc += wr[j] * xr[j];
        acc += ib[30 + o];
        int i = b * HH + dd / HD, hd = dd % HD;
        float* dst = which ? v_all : k_all;
        dst[((size_t)po * NI + i) * (TT * HD) + t * HD + hd] = acc;
    }
}

// q-projection for layer 0 (h == pl). One wave per (s,tb); 4 waves/block.
__global__ __launch_bounds__(256) void lnq0_kernel(
    const float* __restrict__ pl,
    const float* __restrict__ in_w, const float* __restrict__ in_b,
    const float* __restrict__ n1g, const float* __restrict__ n1b,
    float* __restrict__ q) {
    int blk = blockIdx.x;                   // [0,600)
    int s = blk / 300;
    int w = threadIdx.x >> 6, lane = threadIdx.x & 63;
    int tb = (blk % 300) * 4 + w;
    int t = tb / BB, b = tb % BB;
    int po = s * LL;                        // l = 0
    const float* iw = in_w + (size_t)po * 2700;   // rows 0..29
    const float* ib = in_b + (size_t)po * 90;
    const float* g  = n1g + (size_t)po * 30;
    const float* bb = n1b + (size_t)po * 30;
    __shared__ float iwS[900];
    __shared__ float xn[4][30];
    for (int j = threadIdx.x; j < 900; j += 256) iwS[j] = iw[j];
    const float* row = pl + (size_t)tb * 30;
    float xval = (lane < 30) ? row[lane] : 0.f;
    float mean = wsum(xval) * (1.f / 30.f);
    float dv = (lane < 30) ? (xval - mean) : 0.f;
    float var = wsum(dv * dv) * (1.f / 30.f);
    float inv = rsqrtf(var + 1e-5f);
    if (lane < 30) xn[w][lane] = dv * inv * g[lane] + bb[lane];
    __syncthreads();
    int o = lane;
    if (o < 30) {
        const float* wr = iwS + o * 30;
        float acc = 0.f;
        #pragma unroll 6
        for (int j = 0; j < 30; j++) acc += wr[j] * xn[w][j];
        acc = (acc + ib[o]) * 0.40824829046386307f;
        int i = b * HH + o / HD, hd = o % HD;
        q[((size_t)s * NI + i) * (TT * HD) + t * HD + hd] = acc;
    }
}

// Score kernel: block = (s, head i, g); stages ONE head f16 in LDS (7.3 KB),
// 4 waves x 2 a's. Fused scores via mfma_f32_32x32x16_f16; vbar row c=150
// provides the mean for free; softmax; attn = sum_b p*q -> global.
// C/D layout: col = lane&31, row = (reg&3) + 8*(reg>>2) + 4*(lane>>5).
__global__ __launch_bounds__(256) void score_kernel(
    const float* __restrict__ q, const float* __restrict__ k_all,
    const float* __restrict__ v_all, int l, float* __restrict__ attn) {
    int blk = blockIdx.x;                   // [0, 1520)
    int s = blk / 760;
    int rem = blk % 760;
    int i = rem / 19;
    int g = rem % 19;
    int tid = threadIdx.x;
    int wv = tid >> 6, lane = tid & 63;
    int lo = lane & 31, hf = lane >> 5;
    int po = s * LL + l;

    __shared__ __align__(16) _Float16 qsh[NR * RSTR];
    __shared__ __align__(16) _Float16 ksh[NR * RSTR];
    __shared__ __align__(16) _Float16 vsh[NR * RSTR];

    int* qz = (int*)qsh; int* kz = (int*)ksh; int* vz = (int*)vsh;
    for (int idx = tid; idx < NR * RSTR / 2; idx += 256) {
        qz[idx] = 0; kz[idx] = 0; vz[idx] = 0;
    }
    __syncthreads();
    const float* qg = q + (size_t)(s * NI + i) * (TT * HD);
    const float* kg = k_all + (size_t)(po * NI + i) * (TT * HD);
    const float* vg = v_all + (size_t)(po * NI + i) * (TT * HD);
    for (int idx = tid; idx < TT * HD; idx += 256) {
        int dst = (idx / HD) * RSTR + (idx % HD);
        qsh[dst] = (_Float16)qg[idx];
        ksh[dst] = (_Float16)kg[idx];
        vsh[dst] = (_Float16)vg[idx];
    }
    __syncthreads();
    if (wv == 0) {   // vbar row (pre-scaled by 1/150) into vsh row 150
        float v6[6] = {0.f, 0.f, 0.f, 0.f, 0.f, 0.f};
        for (int c = lane; c < TT; c += 64) {
            #pragma unroll
            for (int t = 0; t < 6; t++) v6[t] += (float)vsh[c * RSTR + t];
        }
        #pragma unroll
        for (int m = 32; m > 0; m >>= 1) {
            #pragma unroll
            for (int t = 0; t < 6; t++) v6[t] += __shfl_xor(v6[t], m, 64);
        }
        if (lane < 6) vsh[TT * RSTR + lane] = (_Float16)(v6[lane] * (1.f / TT));
    }
    __syncthreads();

    f32x16 zacc;
    #pragma unroll
    for (int j = 0; j < 16; j++) zacc[j] = 0.f;
    half8 zero8;
    #pragma unroll
    for (int t = 0; t < 8; t++) zero8[t] = (_Float16)0.f;

    half8 bfrag[5], vhalf[5];
    #pragma unroll
    for (int nt = 0; nt < 5; nt++) {
        int rr = nt * 32 + lo;
        int rc = rr < 151 ? rr : 151;          // 150 = vbar, 151 = zeros
        half8 kf = *(const half8*)&ksh[rc * RSTR];
        half8 vf = *(const half8*)&vsh[rc * RSTR];
        bfrag[nt] = hf ? zero8 : kf;
        vhalf[nt] = hf ? zero8 : vf;
    }

    for (int ap = 0; ap < 2; ap++) {
        int a = g * 8 + wv * 2 + ap;
        if (a >= TT) break;
        half8 qav = *(const half8*)&qsh[a * RSTR];
        half8 afrag[5];
        #pragma unroll
        for (int nt = 0; nt < 5; nt++) afrag[nt] = vhalf[nt] * qav;  // v_pk_mul_f16

        float fsc[5];
        #pragma unroll
        for (int nb = 0; nb < 5; nb++) {
            float rm = -INFINITY;
            #pragma unroll
            for (int ma = 0; ma < 4; ma++) {
                f32x16 acc = __builtin_amdgcn_mfma_f32_32x32x16_f16(afrag[ma], bfrag[nb], zacc, 0, 0, 0);
                float m = fmaxf(acc[0], acc[1]);
                #pragma unroll
                for (int j = 2; j < 16; j += 2) m = fmaxf(fmaxf(m, acc[j]), acc[j + 1]);
                rm = fmaxf(rm, m);
            }
            f32x16 a4 = __builtin_amdgcn_mfma_f32_32x32x16_f16(afrag[4], bfrag[nb], zacc, 0, 0, 0);
            // live rows: hf==0 -> regs 0..11 (c<=147); hf==1 -> regs 0..9 (c<=149)
            float m4 = fmaxf(a4[0], a4[1]);
            #pragma unroll
            for (int j = 2; j < 10; j += 2) m4 = fmaxf(fmaxf(m4, a4[j]), a4[j + 1]);
            float ext = (hf == 0) ? fmaxf(a4[10], a4[11]) : -INFINITY;
            rm = fmaxf(rm, fmaxf(m4, ext));
            // mean sits at reg10 of hf==1 lanes (row c==150 = vbar row)
            float om = __shfl_xor(a4[10], 32, 64);
            float mn = hf ? a4[10] : om;
            rm = fmaxf(rm, __shfl_xor(rm, 32, 64));
            int bcol = nb * 32 + lo;
            fsc[nb] = (bcol < TT) ? (mn + rm) : -INFINITY;
        }
        float m = fsc[0];
        #pragma unroll
        for (int nb = 1; nb < 5; nb++) m = fmaxf(m, fsc[nb]);
        #pragma unroll
        for (int msk = 16; msk > 0; msk >>= 1) m = fmaxf(m, __shfl_xor(m, msk, 64));
        float e[5], es = 0.f;
        #pragma unroll
        for (int nb = 0; nb < 5; nb++) { e[nb] = __expf(fsc[nb] - m); es += e[nb]; }
        #pragma unroll
        for (int msk = 16; msk > 0; msk >>= 1) es += __shfl_xor(es, msk, 64);
        float acc6[6] = {0.f, 0.f, 0.f, 0.f, 0.f, 0.f};
        #pragma unroll
        for (int nb = 0; nb < 5; nb++) {
            int bcol = nb * 32 + lo;
            int bi = (bcol < TT) ? bcol : 0;
            float wgt = e[nb];
            half8 qrow = *(const half8*)&qsh[bi * RSTR];
            #pragma unroll
            for (int t = 0; t < 6; t++) acc6[t] += wgt * (float)qrow[t];
        }
        #pragma unroll
        for (int msk = 16; msk > 0; msk >>= 1) {
            #pragma unroll
            for (int t = 0; t < 6; t++) acc6[t] += __shfl_xor(acc6[t], msk, 64);
        }
        if (lane == 0) {
            float inv = 1.f / es;
            int bo = i / HH, ho = i % HH;
            float* dst = attn + (size_t)s * ROWF + a * (BB * DD) + bo * DD + ho * HD;
            #pragma unroll
            for (int t = 0; t < 6; t++) dst[t] = acc6[t] * inv;
        }
    }
}

// FFN for layer l + q-projection for layer l+1 (exact per-row fusion).
// One wave per (s,tb); 4 waves/block; all block-uniform weights staged in LDS.
__global__ __launch_bounds__(256) void ffnlnq_kernel(
    const float* __restrict__ attn, const float* __restrict__ pl,
    const float* __restrict__ out_w, const float* __restrict__ out_b,
    const float* __restrict__ l1w, const float* __restrict__ l1b,
    const float* __restrict__ l2w, const float* __restrict__ l2b,
    const float* __restrict__ n2g, const float* __restrict__ n2b,
    const float* __restrict__ in_w, const float* __restrict__ in_b,
    const float* __restrict__ n1g, const float* __restrict__ n1b,
    int l, int has_next,
    float* __restrict__ h, float* __restrict__ q) {
    int blk = blockIdx.x;                   // [0,600)
    int s = blk / 300;
    int w = threadIdx.x >> 6, lane = threadIdx.x & 63;
    int tb = (blk % 300) * 4 + w;           // [0,1200)
    int t = tb / BB, b = tb % BB;
    int po = s * LL + l;
    const float* ow = out_w + (size_t)po * 900;
    const float* ob = out_b + (size_t)po * 30;
    const float* w1 = l1w + (size_t)po * 3600;
    const float* b1 = l1b + (size_t)po * 120;
    const float* w2 = l2w + (size_t)po * 3600;
    const float* b2 = l2b + (size_t)po * 30;
    const float* g2 = n2g + (size_t)po * 30;
    const float* bb2 = n2b + (size_t)po * 30;
    __shared__ float owS[900];
    __shared__ float w1T[30 * 128];         // transposed: [j][o], stride 128
    __shared__ float w2S[30 * 121];         // row stride 121 -> bank spread
    __shared__ float iwqS[900];
    __shared__ float arS[4][30], xnS[4][32], hidS[4][120], xqS[4][30];
    for (int j = threadIdx.x; j < 900; j += 256) owS[j] = ow[j];
    for (int j = threadIdx.x; j < 3600; j += 256) w1T[(j % 30) * 128 + (j / 30)] = w1[j];
    for (int j = threadIdx.x; j < 3600; j += 256) w2S[(j / 120) * 121 + (j % 120)] = w2[j];
    if (has_next) {
        const float* iwq = in_w + (size_t)(po + 1) * 2700;   // q rows of layer l+1
        for (int j = threadIdx.x; j < 900; j += 256) iwqS[j] = iwq[j];
    }
    __syncthreads();
    float* hrow = h + (size_t)s * ROWF + (size_t)tb * 30;
    const float* res = (l == 0) ? (pl + (size_t)tb * 30) : hrow;
    const float* arow = attn + (size_t)s * ROWF + (size_t)tb * 30;
    if (lane < 30) arS[w][lane] = arow[lane];
    float x1v = 0.f;
    if (lane < 30) {
        const float* wr = owS + lane * 30;
        float acc = 0.f;
        #pragma unroll 6
        for (int j = 0; j < 30; j++) acc += wr[j] * arS[w][j];
        x1v = res[lane] + acc + ob[lane];
    }
    float mean = wsum(x1v) * (1.f / 30.f);
    float dv = (lane < 30) ? (x1v - mean) : 0.f;
    float var = wsum(dv * dv) * (1.f / 30.f);
    float inv = rsqrtf(var + 1e-5f);
    if (lane < 30) xnS[w][lane] = dv * inv * g2[lane] + bb2[lane];
    for (int o = lane; o < 120; o += 64) {
        float acc = 0.f;
        #pragma unroll 6
        for (int j = 0; j < 30; j++) acc += w1T[j * 128 + o] * xnS[w][j];
        hidS[w][o] = fmaxf(acc + b1[o], 0.f);
    }
    float newh = 0.f;
    if (lane < 30) {
        const float* wr = w2S + lane * 121;
        float acc = 0.f;
        #pragma unroll 8
        for (int j = 0; j < 120; j++) acc += wr[j] * hidS[w][j];
        newh = x1v + acc + b2[lane];
        hrow[lane] = newh;
    }
    if (has_next) {
        // LN(newh) with n1 of layer l+1, project q rows 0..29
        const float* g1 = n1g + (size_t)(po + 1) * 30;
        const float* bb1 = n1b + (size_t)(po + 1) * 30;
        const float* ibq = in_b + (size_t)(po + 1) * 90;
        float mean2 = wsum(newh) * (1.f / 30.f);
        float dv2 = (lane < 30) ? (newh - mean2) : 0.f;
        float var2 = wsum(dv2 * dv2) * (1.f / 30.f);
        float inv2 = rsqrtf(var2 + 1e-5f);
        if (lane < 30) xqS[w][lane] = dv2 * inv2 * g1[lane] + bb1[lane];
        int o = lane;
        if (o < 30) {
            const float* wr = iwqS + o * 30;
            float acc = 0.f;
            #pragma unroll 6
            for (int j = 0; j < 30; j++) acc += wr[j] * xqS[w][j];
            acc = (acc + ibq[o]) * 0.40824829046386307f;
            int i = b * HH + o / HD, hd = o % HD;
            q[((size_t)s * NI + i) * (TT * HD) + t * HD + hd] = acc;
        }
    }
}

// Final head: last_hs, proj MLP + residual, scalar out. Writes all 488 outputs.
__global__ __launch_bounds__(256) void head_kernel(
    const float* __restrict__ h,
    const float* __restrict__ p1w, const float* __restrict__ p1b,
    const float* __restrict__ p2w, const float* __restrict__ p2b,
    const float* __restrict__ ow, const float* __restrict__ ob,
    float* __restrict__ out) {
    int tid = threadIdx.x;
    __shared__ float lh[480], hid[480], pr[480];
    for (int idx = tid; idx < 480; idx += 256) {
        int b = idx / 60, j = idx % 60;
        int s = j / 30, d = j % 30;
        float vv = h[(size_t)s * ROWF + 149 * (BB * DD) + b * DD + d];
        lh[idx] = vv;
        out[8 + idx] = vv;   // last_hs output
    }
    __syncthreads();
    for (int idx = tid; idx < 480; idx += 256) {
        int b = idx / 60, o = idx % 60;
        const float* wr = p1w + o * 60;
        float acc = p1b[o];
        for (int j = 0; j < 60; j++) acc += wr[j] * lh[b * 60 + j];
        hid[idx] = fmaxf(acc, 0.f);
    }
    __syncthreads();
    for (int idx = tid; idx < 480; idx += 256) {
        int b = idx / 60, d = idx % 60;
        const float* wr = p2w + d * 60;
        float acc = p2b[d];
        for (int j = 0; j < 60; j++) acc += wr[j] * hid[b * 60 + j];
        pr[idx] = acc + lh[idx];
    }
    __syncthreads();
    if (tid < 8) {
        float acc = ob[0];
        for (int j = 0; j < 60; j++) acc += pr[tid * 60 + j] * ow[j];
        out[tid] = acc;     // out output
    }
}

extern "C" void kernel_launch(void* const* d_in, const int* in_sizes, int n_in,
                              void* d_out, int out_size, void* d_ws, size_t ws_size,
                              hipStream_t stream) {
    const float* x_l   = (const float*)d_in[0];
    const float* x_a   = (const float*)d_in[1];
    const float* x_v   = (const float*)d_in[2];
    const float* Wl    = (const float*)d_in[3];
    const float* Wa    = (const float*)d_in[4];
    const float* Wv    = (const float*)d_in[5];
    const float* in_w  = (const float*)d_in[6];
    const float* in_b  = (const float*)d_in[7];
    const float* out_w = (const float*)d_in[8];
    const float* out_b = (const float*)d_in[9];
    const float* l1w   = (const float*)d_in[10];
    const float* l1b   = (const float*)d_in[11];
    const float* l2w   = (const float*)d_in[12];
    const float* l2b   = (const float*)d_in[13];
    const float* n1g   = (const float*)d_in[14];
    const float* n1b   = (const float*)d_in[15];
    const float* n2g   = (const float*)d_in[16];
    const float* n2b   = (const float*)d_in[17];
    const float* p1w   = (const float*)d_in[18];
    const float* p1b   = (const float*)d_in[19];
    const float* p2w   = (const float*)d_in[20];
    const float* p2b   = (const float*)d_in[21];
    const float* oww   = (const float*)d_in[22];
    const float* obb   = (const float*)d_in[23];

    float* ws = (float*)d_ws;
    float* pl    = ws;             // 36000
    float* pa    = ws + 36000;     // 36000
    float* pv    = ws + 72000;     // 36000
    float* h     = ws + 108000;    // 72000  [2][T][B][D]
    float* q     = ws + 180000;    // 72000  [2][NI][TT][HD]
    float* k_all = ws + 252000;    // 216000 [6][NI][TT][HD]
    float* v_all = ws + 468000;    // 216000
    float* at    = ws + 684000;    // 72000

    proj3_kernel<<<900, 256, 0, stream>>>(x_l, x_a, x_v, Wl, Wa, Wv, pl, pa, pv);
    kvpre_kernel<<<1800, 256, 0, stream>>>(pa, pv, in_w, in_b, n1g, n1b, k_all, v_all);
    lnq0_kernel<<<600, 256, 0, stream>>>(pl, in_w, in_b, n1g, n1b, q);

    for (int l = 0; l < LL; l++) {
        score_kernel<<<1520, 256, 0, stream>>>(q, k_all, v_all, l, at);
        ffnlnq_kernel<<<600, 256, 0, stream>>>(at, pl, out_w, out_b, l1w, l1b, l2w, l2b,
                                               n2g, n2b, in_w, in_b, n1g, n1b,
                                               l, (l < LL - 1) ? 1 : 0, h, q);
    }
    head_kernel<<<1, 256, 0, stream>>>(h, p1w, p1b, p2w, p2b, oww, obb, (float*)d_out);
}